// Round 4
// baseline (438.006 us; speedup 1.0000x reference)
//
#include <hip/hip_runtime.h>
#include <math.h>

#define NF 4096   // ifft length (dot axis)
#define NC 256    // scan axis length
#define NJ 512    // fft output length
#define CH 128    // gram m-chunk size
#define PI_F 3.14159265358979323846f

__device__ __forceinline__ float2 cmul(float2 a, float2 b) {
    return make_float2(a.x*b.x - a.y*b.y, a.x*b.y + a.y*b.x);
}

// ---------------- stage B: IFFT-4096 per (b,c) column, Stockham radix-2 (verified at N=4) ----------------
// p=1..N/2: k=i&(p-1); t1 = e^{+i*pi*k/p} * X[i+N/2]; Y[2i-k]=X[i]+t1; Y[2i-k+p]=X[i]-t1.
__global__ __launch_bounds__(256) void ifft4096_kernel(const float* __restrict__ xr,
                                                       const float* __restrict__ xi,
                                                       float2* __restrict__ fin,
                                                       int b0, int bmask, int bshift) {
    __shared__ float2 bufA[NF];   // 32 KiB
    __shared__ float2 bufB[NF];   // 32 KiB
    int wg = blockIdx.x;
    int bl = wg & bmask;          // local batch (fast index -> XCD spread)
    int c = wg >> bshift;
    int t = threadIdx.x;
    const float scale = 1.0f / (4096.0f * 1.5f);   // ifft 1/N * 1/denom
    int bg = b0 + bl;
#pragma unroll
    for (int q = 0; q < 16; q++) {
        int f = t + 256 * q;
        size_t idx = ((size_t)(bg * NF + f)) * NC + c;   // x[b, f, c]
        bufA[f] = make_float2(xr[idx] * scale, xi[idx] * scale);
    }
    __syncthreads();
    float2* X = bufA;
    float2* Y = bufB;
    for (int p = 1; p <= 2048; p <<= 1) {
        float invp = PI_F / (float)p;
#pragma unroll
        for (int q = 0; q < 8; q++) {
            int i = t + 256 * q;
            int k = i & (p - 1);
            float2 u0 = X[i];
            float2 u1 = X[i + 2048];
            float sn, cs;
            __sincosf(invp * (float)k, &sn, &cs);
            float2 t1 = cmul(u1, make_float2(cs, sn));
            int j = 2 * i - k;
            Y[j]     = make_float2(u0.x + t1.x, u0.y + t1.y);
            Y[j + p] = make_float2(u0.x - t1.x, u0.y - t1.y);
        }
        __syncthreads();
        float2* tmp = X; X = Y; Y = tmp;
    }
    // 12 stages (even swap count) -> result in bufA == X
    size_t obase = ((size_t)(bl * NC + c)) * NF;
#pragma unroll
    for (int q = 0; q < 16; q++) {
        int f = t + 256 * q;
        fin[obase + f] = X[f];
    }
}

// ---------------- stage C1: banded Gram partials G[k][d] = <f_{k-d}, f_k>, per m-chunk ----------------
__global__ __launch_bounds__(256) void gram_kernel(const float2* __restrict__ fin,
                                                   float2* __restrict__ gpart) {
    __shared__ float2 ring[16][CH];   // 16 KiB
    int wg = blockIdx.x;            // bl*32 + ch
    int bl = wg >> 5;
    int ch = wg & 31;
    int m0 = ch * CH;
    int t = threadIdx.x;
    int dgrp = t >> 5;              // 0..7 -> d = dgrp+1
    int lane = t & 31;
    if (t < CH) ring[0][t] = fin[((size_t)(bl * NC)) * NF + m0 + t];
    __syncthreads();
    for (int k = 0; k < NC; k++) {
        float2 nxt;
        if (k + 1 < NC && t < CH)
            nxt = fin[((size_t)(bl * NC + k + 1)) * NF + m0 + t];
        int d = dgrp + 1;
        float2 acc = make_float2(0.f, 0.f);
        if (k - d >= 0) {
            int sk = k & 15, sj = (k - d) & 15;
#pragma unroll
            for (int i = 0; i < 4; i++) {
                int m = lane + 32 * i;
                float2 a = ring[sj][m];   // f_{k-d}
                float2 bb = ring[sk][m];  // f_k
                acc.x += a.x * bb.x + a.y * bb.y;   // conj(a)*b
                acc.y += a.x * bb.y - a.y * bb.x;
            }
        }
#pragma unroll
        for (int off = 16; off >= 1; off >>= 1) {
            acc.x += __shfl_xor(acc.x, off);
            acc.y += __shfl_xor(acc.y, off);
        }
        if (lane == 0)   // all (k,d) written; d>k rows exact zeros -> no poison downstream
            gpart[((size_t)wg * NC + k) * 8 + dgrp] = acc;
        if (k + 1 < NC && t < CH)
            ring[(k + 1) & 15][t] = nxt;
        __syncthreads();
    }
}

// ---------------- stage C2a: sum Gram partials over 32 chunks ----------------
__global__ void gsum_kernel(const float2* __restrict__ gpart, float2* __restrict__ gs, int total) {
    int e = blockIdx.x * blockDim.x + threadIdx.x;   // (bl, k, d)
    if (e >= total) return;
    int bl = e >> 11;            // 2048 = 256*8 entries per batch
    int kd = e & 2047;
    float2 s = make_float2(0.f, 0.f);
    for (int ch = 0; ch < 32; ch++) {
        float2 v = gpart[((size_t)(bl * 32 + ch)) * 2048 + kd];
        s.x += v.x; s.y += v.y;
    }
    gs[e] = s;
}

// ---------------- stage C2b: scalar phase recurrence ----------------
__global__ void scan_kernel(const float2* __restrict__ gs, float2* __restrict__ phase, int nb) {
    int bl = threadIdx.x;
    if (bl >= nb) return;
    float2 p1 = make_float2(1.f, 0.f);
    float2 z = make_float2(0.f, 0.f);
    float2 p2 = z, p3 = z, p4 = z, p5 = z, p6 = z, p7 = z, p8 = z;
    phase[bl * NC] = p1;
    for (int k = 1; k < NC; k++) {
        const float2* g = &gs[((size_t)bl * NC + k) * 8];
        float2 g0 = g[0], g1 = g[1], g2 = g[2], g3 = g[3];
        float2 g4 = g[4], g5 = g[5], g6 = g[6], g7 = g[7];
        float2 s = make_float2(0.f, 0.f);
        s.x += p1.x*g0.x - p1.y*g0.y; s.y += p1.x*g0.y + p1.y*g0.x;
        s.x += p2.x*g1.x - p2.y*g1.y; s.y += p2.x*g1.y + p2.y*g1.x;
        s.x += p3.x*g2.x - p3.y*g2.y; s.y += p3.x*g2.y + p3.y*g2.x;
        s.x += p4.x*g3.x - p4.y*g3.y; s.y += p4.x*g3.y + p4.y*g3.x;
        s.x += p5.x*g4.x - p5.y*g4.y; s.y += p5.x*g4.y + p5.y*g4.x;
        s.x += p6.x*g5.x - p6.y*g5.y; s.y += p6.x*g5.y + p6.y*g5.x;
        s.x += p7.x*g6.x - p7.y*g6.y; s.y += p7.x*g6.y + p7.y*g6.x;
        s.x += p8.x*g7.x - p8.y*g7.y; s.y += p8.x*g7.y + p8.y*g7.x;
        float inv = 1.0f / sqrtf(s.x * s.x + s.y * s.y);
        float2 np = make_float2(s.x * inv, s.y * inv);
        phase[bl * NC + k] = np;
        p8 = p7; p7 = p6; p6 = p5; p5 = p4; p4 = p3; p3 = p2; p2 = p1; p1 = np;
    }
}

// ---------------- stage C3: fin *= conj(phase) in place ----------------
__global__ void scale_kernel(float4* __restrict__ fin4, const float2* __restrict__ phase, int n4) {
    int i = blockIdx.x * blockDim.x + threadIdx.x;
    if (i >= n4) return;
    int row = i >> 11;            // 2048 float4 per (bl,c) row
    float2 ph = phase[row];
    float4 v = fin4[i];
    fin4[i] = make_float4(v.x*ph.x + v.y*ph.y, v.y*ph.x - v.x*ph.y,
                          v.z*ph.x + v.w*ph.y, v.w*ph.x - v.z*ph.y);
}

// ---------------- stage D: FFT-512 over c (zero-padded), transposed store ----------------
#define FT 8
#define LDSP 9
__global__ __launch_bounds__(256) void fft512_kernel(const float2* __restrict__ fin,
                                                     float* __restrict__ outr,
                                                     float2* __restrict__ outc,
                                                     int b0, int realOnly) {
    __shared__ float2 ld[NJ * LDSP];   // 36 KiB
    int wg = blockIdx.x;               // bl*512 + ftile
    int bl = wg >> 9;
    int f0 = (wg & 511) * FT;
    int t = threadIdx.x;
    int fp = t & 7;
    int cg = t >> 3;                   // 0..31
    // bit-reversed load (c<256 -> even positions); zero-pad odd positions
#pragma unroll
    for (int it = 0; it < 8; it++) {
        int c = it * 32 + cg;
        float2 o = fin[((size_t)(bl * NC + c)) * NF + f0 + fp];
        int pos = __brev((unsigned)c) >> 23;   // brev9, even for c<256
        ld[pos * LDSP + fp] = o;
        ld[(pos + 1) * LDSP + fp] = make_float2(0.f, 0.f);
    }
    __syncthreads();
    // 9 in-place DIT stages, sign -1 (forward fft)
    for (int st = 0; st < 9; st++) {
        int half = 1 << st;
        float angc = -PI_F / (float)half;
#pragma unroll
        for (int q = 0; q < 8; q++) {
            int u = t + 256 * q;
            int fp2 = u & 7;
            int p = u >> 3;
            int i = p & (half - 1);
            int base = ((p >> st) << (st + 1)) + i;
            float sn, cs;
            __sincosf(angc * (float)i, &sn, &cs);
            float2 w = make_float2(cs, sn);
            float2 a = ld[base * LDSP + fp2];
            float2 bb = ld[(base + half) * LDSP + fp2];
            float2 tt = cmul(bb, w);
            ld[base * LDSP + fp2]          = make_float2(a.x + tt.x, a.y + tt.y);
            ld[(base + half) * LDSP + fp2] = make_float2(a.x - tt.x, a.y - tt.y);
        }
        __syncthreads();
    }
    // store: out3[(b*4096 + m)*512 + j], j fastest -> coalesced
    size_t ob = ((size_t)((b0 + bl) * NF + f0)) * NJ;
    if (realOnly) {
#pragma unroll
        for (int fp2 = 0; fp2 < FT; fp2++)
#pragma unroll
            for (int jq = 0; jq < 2; jq++) {
                int j = t + 256 * jq;
                outr[ob + (size_t)fp2 * NJ + j] = ld[j * LDSP + fp2].x;
            }
    } else {
#pragma unroll
        for (int fp2 = 0; fp2 < FT; fp2++)
#pragma unroll
            for (int jq = 0; jq < 2; jq++) {
                int j = t + 256 * jq;
                outc[ob + (size_t)fp2 * NJ + j] = ld[j * LDSP + fp2];
            }
    }
}

// ---------------- output 0 writers (run LAST) ----------------
__global__ void copy_kernel(const float4* __restrict__ src, float4* __restrict__ dst, int n4) {
    int i = blockIdx.x * blockDim.x + threadIdx.x;
    int stride = gridDim.x * blockDim.x;
    for (; i < n4; i += stride) dst[i] = src[i];
}
__global__ void pack_x_kernel(const float2* __restrict__ xr, const float2* __restrict__ xi,
                              float4* __restrict__ out, int n4) {
    int i = blockIdx.x * blockDim.x + threadIdx.x;
    int stride = gridDim.x * blockDim.x;
    for (; i < n4; i += stride) {
        float2 r = xr[i], m = xi[i];
        out[i] = make_float4(r.x, m.x, r.y, m.y);
    }
}

extern "C" void kernel_launch(void* const* d_in, const int* in_sizes, int n_in,
                              void* d_out, int out_size, void* d_ws, size_t ws_size,
                              hipStream_t stream) {
    const float* xr = (const float*)d_in[0];
    const float* xi = (const float*)d_in[1];
    float* out = (float*)d_out;

    if (out_size < 40000000) {
        // ---- real-only outputs: out0 = x_real (8388608 f), out3 = Re(out3) (16777216 f) ----
        float* out0r = out;
        float* out3r = out + 8388608;
        size_t need = (size_t)(8388608 + 524288 + 16384 + 2048) * sizeof(float2); // ~68.2 MiB
        if (ws_size >= need) {
            // single pass, all scratch in d_ws
            float2* fin   = (float2*)d_ws;
            float2* gpart = fin + 8388608;
            float2* gsb   = gpart + 524288;
            float2* phase = gsb + 16384;
            ifft4096_kernel<<<8 * NC, 256, 0, stream>>>(xr, xi, fin, 0, 7, 3);
            gram_kernel<<<8 * 32, 256, 0, stream>>>(fin, gpart);
            gsum_kernel<<<(8 * 2048) / 256, 256, 0, stream>>>(gpart, gsb, 8 * 2048);
            scan_kernel<<<1, 64, 0, stream>>>(gsb, phase, 8);
            scale_kernel<<<8 * 2048, 256, 0, stream>>>((float4*)fin, phase, 8 * 524288);
            fft512_kernel<<<8 * 512, 256, 0, stream>>>(fin, out3r, nullptr, 0, 1);
        } else {
            // two passes over batch halves; fin fills out0 region exactly (4194304 float2);
            // gram scratch in out3 tail (float2 offset >= 4194304, clobbered only by pass-2 fft512
            // AFTER it is consumed).
            float2* fin   = (float2*)out0r;                 // 4194304 float2 = 33.55 MB
            float2* o3f2  = (float2*)out3r;                 // region viewed as 8388608 float2
            float2* gpart = o3f2 + (8388608 - 262144 - 8192 - 1024);
            float2* gsb   = o3f2 + (8388608 - 8192 - 1024);
            float2* phase = o3f2 + (8388608 - 1024);
            for (int p = 0; p < 2; p++) {
                int b0 = p * 4;
                ifft4096_kernel<<<4 * NC, 256, 0, stream>>>(xr, xi, fin, b0, 3, 2);
                gram_kernel<<<4 * 32, 256, 0, stream>>>(fin, gpart);
                gsum_kernel<<<(4 * 2048) / 256, 256, 0, stream>>>(gpart, gsb, 4 * 2048);
                scan_kernel<<<1, 64, 0, stream>>>(gsb, phase, 4);
                scale_kernel<<<4 * 2048, 256, 0, stream>>>((float4*)fin, phase, 4 * 524288);
                fft512_kernel<<<4 * 512, 256, 0, stream>>>(fin, out3r, nullptr, b0, 1);
            }
        }
        copy_kernel<<<2048, 256, 0, stream>>>((const float4*)xr, (float4*)out0r, 2097152);
    } else {
        // ---- defensive path: complex outputs stored as float pairs (round-3 layout) ----
        float2* out0f2 = (float2*)out;                 // 8388608 float2
        float2* out3f2 = (float2*)(out + 16777216);    // 16777216 float2
        float2* fin   = out0f2;
        float2* gpart = out3f2 + (16777216 - 524288 - 16384 - 2048);
        float2* gsb   = out3f2 + (16777216 - 16384 - 2048);
        float2* phase = out3f2 + (16777216 - 2048);
        ifft4096_kernel<<<8 * NC, 256, 0, stream>>>(xr, xi, fin, 0, 7, 3);
        gram_kernel<<<8 * 32, 256, 0, stream>>>(fin, gpart);
        gsum_kernel<<<(8 * 2048) / 256, 256, 0, stream>>>(gpart, gsb, 8 * 2048);
        scan_kernel<<<1, 64, 0, stream>>>(gsb, phase, 8);
        scale_kernel<<<8 * 2048, 256, 0, stream>>>((float4*)fin, phase, 8 * 524288);
        fft512_kernel<<<8 * 512, 256, 0, stream>>>(fin, nullptr, out3f2, 0, 0);
        pack_x_kernel<<<4096, 256, 0, stream>>>((const float2*)xr, (const float2*)xi,
                                                (float4*)out0f2, 4194304);
    }
}

// Round 5
// 310.433 us; speedup vs baseline: 1.4110x; 1.4110x over previous
//
#include <hip/hip_runtime.h>
#include <math.h>

#define NF 4096   // ifft length (dot axis)
#define NC 256    // scan axis length
#define NJ 512    // fft output length
#define CH 128    // gram m-chunk size
#define TWO_PI_F 6.28318530717958647692f

__device__ __forceinline__ float2 cmul(float2 a, float2 b) {
    return make_float2(a.x*b.x - a.y*b.y, a.x*b.y + a.y*b.x);
}

// ---------- register DFT primitives (verified with delta inputs) ----------
__device__ __forceinline__ void dft4i(float2& x0, float2& x1, float2& x2, float2& x3, float sgn) {
    float2 t0 = make_float2(x0.x + x2.x, x0.y + x2.y);
    float2 t1 = make_float2(x0.x - x2.x, x0.y - x2.y);
    float2 t2 = make_float2(x1.x + x3.x, x1.y + x3.y);
    float2 t3 = make_float2(x1.x - x3.x, x1.y - x3.y);
    float2 it3 = make_float2(-sgn * t3.y, sgn * t3.x);   // sgn*i*t3
    x0 = make_float2(t0.x + t2.x, t0.y + t2.y);
    x2 = make_float2(t0.x - t2.x, t0.y - t2.y);
    x1 = make_float2(t1.x + it3.x, t1.y + it3.y);
    x3 = make_float2(t1.x - it3.x, t1.y - it3.y);
}

// natural-order DFT16 in registers; v_j ends up in slot 4*(j&3) + (j>>2)
__device__ __forceinline__ void dft16(float2* u, float sgn) {
    dft4i(u[0], u[4], u[8],  u[12], sgn);
    dft4i(u[1], u[5], u[9],  u[13], sgn);
    dft4i(u[2], u[6], u[10], u[14], sgn);
    dft4i(u[3], u[7], u[11], u[15], sgn);
    const float C1 = 0.9238795325112867f, S1 = 0.3826834323650898f, R2 = 0.7071067811865476f;
    u[5]  = cmul(u[5],  make_float2(C1,  sgn * S1));
    u[6]  = cmul(u[6],  make_float2(R2,  sgn * R2));
    u[7]  = cmul(u[7],  make_float2(S1,  sgn * C1));
    u[9]  = cmul(u[9],  make_float2(R2,  sgn * R2));
    u[10] = cmul(u[10], make_float2(0.f, sgn));
    u[11] = cmul(u[11], make_float2(-R2, sgn * R2));
    u[13] = cmul(u[13], make_float2(S1,  sgn * C1));
    u[14] = cmul(u[14], make_float2(-R2, sgn * R2));
    u[15] = cmul(u[15], make_float2(-C1, -sgn * S1));
    dft4i(u[0],  u[1],  u[2],  u[3],  sgn);
    dft4i(u[4],  u[5],  u[6],  u[7],  sgn);
    dft4i(u[8],  u[9],  u[10], u[11], sgn);
    dft4i(u[12], u[13], u[14], u[15], sgn);
}

// natural-order DFT8: out v[0..7] from in u[0..7]
__device__ __forceinline__ void dft8(const float2* u, float2* v, float sgn) {
    float2 e0 = u[0], e1 = u[2], e2 = u[4], e3 = u[6];
    float2 o0 = u[1], o1 = u[3], o2 = u[5], o3 = u[7];
    dft4i(e0, e1, e2, e3, sgn);
    dft4i(o0, o1, o2, o3, sgn);
    const float R2 = 0.7071067811865476f;
    float2 w1 = make_float2(R2, sgn * R2);
    float2 w2 = make_float2(0.f, sgn);
    float2 w3 = make_float2(-R2, sgn * R2);
    float2 t1 = cmul(o1, w1), t2 = cmul(o2, w2), t3 = cmul(o3, w3);
    v[0] = make_float2(e0.x + o0.x, e0.y + o0.y);
    v[4] = make_float2(e0.x - o0.x, e0.y - o0.y);
    v[1] = make_float2(e1.x + t1.x, e1.y + t1.y);
    v[5] = make_float2(e1.x - t1.x, e1.y - t1.y);
    v[2] = make_float2(e2.x + t2.x, e2.y + t2.y);
    v[6] = make_float2(e2.x - t2.x, e2.y - t2.y);
    v[3] = make_float2(e3.x + t3.x, e3.y + t3.y);
    v[7] = make_float2(e3.x - t3.x, e3.y - t3.y);
}

// ---------------- stage B: IFFT-4096, Stockham radix-16, 3 passes in-place ----------------
#define IPAD(a) ((a) + ((a) >> 4))

template<int P>
__device__ __forceinline__ void pass16(float2* S, int t, float sgn) {
    const int k = t & (P - 1);
    float2 u[16];
#pragma unroll
    for (int r = 0; r < 16; r++) u[r] = S[IPAD(t + 256 * r)];
    __syncthreads();
    if (P > 1) {
        float ab = sgn * (TWO_PI_F / (16.0f * (float)P)) * (float)k;
#pragma unroll
        for (int r = 1; r < 16; r++) {
            float sn, cs; __sincosf(ab * (float)r, &sn, &cs);
            u[r] = cmul(u[r], make_float2(cs, sn));
        }
    }
    dft16(u, sgn);
    const int base = 16 * P * (t / P) + k;
#pragma unroll
    for (int j = 0; j < 16; j++) {
        const int sl = ((j & 3) << 2) | (j >> 2);
        S[IPAD(base + j * P)] = u[sl];
    }
    __syncthreads();
}

__global__ __launch_bounds__(256) void ifft4096_kernel(const float* __restrict__ xr,
                                                       const float* __restrict__ xi,
                                                       float2* __restrict__ fin,
                                                       int b0, int bmask, int bshift) {
    __shared__ float2 S[4352];   // 4096 + 256 pad = 34 KiB
    int wg = blockIdx.x;
    int bl = wg & bmask;
    int c = wg >> bshift;
    int t = threadIdx.x;
    const float scale = 1.0f / (4096.0f * 1.5f);
    int bg = b0 + bl;
#pragma unroll
    for (int q = 0; q < 16; q++) {
        int f = t + 256 * q;
        size_t idx = ((size_t)(bg * NF + f)) * NC + c;
        S[IPAD(f)] = make_float2(xr[idx] * scale, xi[idx] * scale);
    }
    __syncthreads();
    pass16<1>(S, t, 1.0f);
    pass16<16>(S, t, 1.0f);
    pass16<256>(S, t, 1.0f);
    size_t obase = ((size_t)(bl * NC + c)) * NF;
#pragma unroll
    for (int q = 0; q < 16; q++) {
        int f = t + 256 * q;
        fin[obase + f] = S[IPAD(f)];
    }
}

// ---------------- stage C1: banded Gram partials, k-segmented ----------------
__global__ __launch_bounds__(256) void gram_kernel(const float2* __restrict__ fin,
                                                   float2* __restrict__ gpart) {
    __shared__ float2 ring[16][CH];
    int wg = blockIdx.x;            // bl*128 + ch*4 + ks
    int bl = wg >> 7;
    int ch = (wg >> 2) & 31;
    int ks = wg & 3;
    int m0 = ch * CH;
    int k0 = ks * 64;
    int kend = k0 + 64;
    int t = threadIdx.x;
    int dgrp = t >> 5;              // 0..7 -> d = dgrp+1
    int lane = t & 31;
    for (int r = (k0 >= 8 ? k0 - 8 : 0); r <= k0; r++)
        if (t < CH) ring[r & 15][t] = fin[((size_t)(bl * NC + r)) * NF + m0 + t];
    __syncthreads();
    for (int k = k0; k < kend; k++) {
        float2 nxt;
        bool ld = (k + 1 < kend) && (t < CH);
        if (ld) nxt = fin[((size_t)(bl * NC + k + 1)) * NF + m0 + t];
        int d = dgrp + 1;
        float2 acc = make_float2(0.f, 0.f);
        if (k - d >= 0) {
            int sk = k & 15, sj = (k - d) & 15;
#pragma unroll
            for (int i = 0; i < 4; i++) {
                int m = lane + 32 * i;
                float2 a = ring[sj][m];
                float2 bb = ring[sk][m];
                acc.x += a.x * bb.x + a.y * bb.y;
                acc.y += a.x * bb.y - a.y * bb.x;
            }
        }
#pragma unroll
        for (int off = 16; off >= 1; off >>= 1) {
            acc.x += __shfl_xor(acc.x, off);
            acc.y += __shfl_xor(acc.y, off);
        }
        if (lane == 0)
            gpart[((size_t)(bl * 32 + ch) * NC + k) * 8 + dgrp] = acc;
        if (ld) ring[(k + 1) & 15][t] = nxt;
        __syncthreads();
    }
}

// ---------------- stage C2a: sum Gram partials over 32 chunks ----------------
__global__ void gsum_kernel(const float2* __restrict__ gpart, float2* __restrict__ gs, int total) {
    int e = blockIdx.x * blockDim.x + threadIdx.x;
    if (e >= total) return;
    int bl = e >> 11;
    int kd = e & 2047;
    float2 s = make_float2(0.f, 0.f);
    for (int ch = 0; ch < 32; ch++) {
        float2 v = gpart[((size_t)(bl * 32 + ch)) * 2048 + kd];
        s.x += v.x; s.y += v.y;
    }
    gs[e] = s;
}

// ---------------- stage C2b: scalar phase recurrence ----------------
__global__ void scan_kernel(const float2* __restrict__ gs, float2* __restrict__ phase, int nb) {
    int bl = threadIdx.x;
    if (bl >= nb) return;
    float2 p1 = make_float2(1.f, 0.f);
    float2 z = make_float2(0.f, 0.f);
    float2 p2 = z, p3 = z, p4 = z, p5 = z, p6 = z, p7 = z, p8 = z;
    phase[bl * NC] = p1;
    for (int k = 1; k < NC; k++) {
        const float2* g = &gs[((size_t)bl * NC + k) * 8];
        float2 g0 = g[0], g1 = g[1], g2 = g[2], g3 = g[3];
        float2 g4 = g[4], g5 = g[5], g6 = g[6], g7 = g[7];
        float2 s = make_float2(0.f, 0.f);
        s.x += p1.x*g0.x - p1.y*g0.y; s.y += p1.x*g0.y + p1.y*g0.x;
        s.x += p2.x*g1.x - p2.y*g1.y; s.y += p2.x*g1.y + p2.y*g1.x;
        s.x += p3.x*g2.x - p3.y*g2.y; s.y += p3.x*g2.y + p3.y*g2.x;
        s.x += p4.x*g3.x - p4.y*g3.y; s.y += p4.x*g3.y + p4.y*g3.x;
        s.x += p5.x*g4.x - p5.y*g4.y; s.y += p5.x*g4.y + p5.y*g4.x;
        s.x += p6.x*g5.x - p6.y*g5.y; s.y += p6.x*g5.y + p6.y*g5.x;
        s.x += p7.x*g6.x - p7.y*g6.y; s.y += p7.x*g6.y + p7.y*g6.x;
        s.x += p8.x*g7.x - p8.y*g7.y; s.y += p8.x*g7.y + p8.y*g7.x;
        float inv = 1.0f / sqrtf(s.x * s.x + s.y * s.y);
        float2 np = make_float2(s.x * inv, s.y * inv);
        phase[bl * NC + k] = np;
        p8 = p7; p7 = p6; p6 = p5; p5 = p4; p4 = p3; p3 = p2; p2 = p1; p1 = np;
    }
}

// ---------------- stage C3 (fallback paths only): fin *= conj(phase) ----------------
__global__ void scale_kernel(float4* __restrict__ fin4, const float2* __restrict__ phase, int n4) {
    int i = blockIdx.x * blockDim.x + threadIdx.x;
    if (i >= n4) return;
    int row = i >> 11;
    float2 ph = phase[row];
    float4 v = fin4[i];
    fin4[i] = make_float4(v.x*ph.x + v.y*ph.y, v.y*ph.x - v.x*ph.y,
                          v.z*ph.x + v.w*ph.y, v.w*ph.x - v.z*ph.y);
}

// ---------------- stage D: FFT-512 over c (zero-padded), Stockham radix-8, fused conj(phase) ----------------
#define FPAD 516   // row stride (float2) for [8][516] LDS

template<int P, bool ZTOP>
__device__ __forceinline__ void pass8x(float2* L, int fp, int i2, float sgn) {
    const int ia = i2, ib = i2 + 32;
    const int ka = ia & (P - 1), kb = ib & (P - 1);
    float2 ua[8], ub[8];
#pragma unroll
    for (int r = 0; r < 8; r++) {
        if (ZTOP && r >= 4) {
            ua[r] = make_float2(0.f, 0.f);
            ub[r] = make_float2(0.f, 0.f);
        } else {
            ua[r] = L[fp * FPAD + ia + 64 * r];
            ub[r] = L[fp * FPAD + ib + 64 * r];
        }
    }
    __syncthreads();
    if (P > 1) {
        float aba = sgn * (TWO_PI_F / (8.0f * (float)P)) * (float)ka;
        float abb = sgn * (TWO_PI_F / (8.0f * (float)P)) * (float)kb;
#pragma unroll
        for (int r = 1; r < 8; r++) {
            float sn, cs;
            __sincosf(aba * (float)r, &sn, &cs);
            ua[r] = cmul(ua[r], make_float2(cs, sn));
            __sincosf(abb * (float)r, &sn, &cs);
            ub[r] = cmul(ub[r], make_float2(cs, sn));
        }
    }
    float2 va[8], vb[8];
    dft8(ua, va, sgn);
    dft8(ub, vb, sgn);
    const int basea = 8 * P * (ia / P) + ka;
    const int baseb = 8 * P * (ib / P) + kb;
#pragma unroll
    for (int r = 0; r < 8; r++) {
        L[fp * FPAD + basea + r * P] = va[r];
        L[fp * FPAD + baseb + r * P] = vb[r];
    }
    __syncthreads();
}

__global__ __launch_bounds__(256) void fft512_kernel(const float2* __restrict__ fin,
                                                     const float2* __restrict__ ph,   // may be null
                                                     float* __restrict__ outr,
                                                     float2* __restrict__ outc,
                                                     int b0, int realOnly) {
    __shared__ float2 L[8 * FPAD];   // 33 KiB
    int wg = blockIdx.x;             // bl*512 + ftile
    int bl = wg >> 9;
    int f0 = (wg & 511) * 8;
    int t = threadIdx.x;
    int fpp = t & 7;
    int cg = t >> 3;                 // 0..31
#pragma unroll
    for (int it = 0; it < 8; it++) {
        int c = it * 32 + cg;
        float2 v = fin[((size_t)(bl * NC + c)) * NF + f0 + fpp];
        if (ph) {
            float2 p = ph[bl * NC + c];
            v = make_float2(v.x * p.x + v.y * p.y, v.y * p.x - v.x * p.y);  // f*conj(ph)
        }
        L[fpp * FPAD + c] = v;
    }
    __syncthreads();
    int fp = t & 7;
    int i2 = t >> 3;                 // 0..31
    pass8x<1, true >(L, fp, i2, -1.0f);
    pass8x<8, false>(L, fp, i2, -1.0f);
    pass8x<64, false>(L, fp, i2, -1.0f);
    size_t ob = ((size_t)((b0 + bl) * NF + f0)) * NJ;
    if (realOnly) {
#pragma unroll
        for (int fp2 = 0; fp2 < 8; fp2++)
#pragma unroll
            for (int jq = 0; jq < 2; jq++) {
                int j = t + 256 * jq;
                outr[ob + (size_t)fp2 * NJ + j] = L[fp2 * FPAD + j].x;
            }
    } else {
#pragma unroll
        for (int fp2 = 0; fp2 < 8; fp2++)
#pragma unroll
            for (int jq = 0; jq < 2; jq++) {
                int j = t + 256 * jq;
                outc[ob + (size_t)fp2 * NJ + j] = L[fp2 * FPAD + j];
            }
    }
}

// ---------------- output 0 writers (run LAST) ----------------
__global__ void copy_kernel(const float4* __restrict__ src, float4* __restrict__ dst, int n4) {
    int i = blockIdx.x * blockDim.x + threadIdx.x;
    int stride = gridDim.x * blockDim.x;
    for (; i < n4; i += stride) dst[i] = src[i];
}
__global__ void pack_x_kernel(const float2* __restrict__ xr, const float2* __restrict__ xi,
                              float4* __restrict__ out, int n4) {
    int i = blockIdx.x * blockDim.x + threadIdx.x;
    int stride = gridDim.x * blockDim.x;
    for (; i < n4; i += stride) {
        float2 r = xr[i], m = xi[i];
        out[i] = make_float4(r.x, m.x, r.y, m.y);
    }
}

extern "C" void kernel_launch(void* const* d_in, const int* in_sizes, int n_in,
                              void* d_out, int out_size, void* d_ws, size_t ws_size,
                              hipStream_t stream) {
    const float* xr = (const float*)d_in[0];
    const float* xi = (const float*)d_in[1];
    float* out = (float*)d_out;

    if (out_size < 40000000) {
        // real-only outputs: out0 = x_real (8388608 f), out3 = Re(out3) (16777216 f)
        float* out0r = out;
        float* out3r = out + 8388608;
        size_t need = (size_t)(8388608 + 524288 + 16384 + 2048) * sizeof(float2);
        if (ws_size >= need) {
            float2* fin   = (float2*)d_ws;
            float2* gpart = fin + 8388608;
            float2* gsb   = gpart + 524288;
            float2* phase = gsb + 16384;
            ifft4096_kernel<<<8 * NC, 256, 0, stream>>>(xr, xi, fin, 0, 7, 3);
            gram_kernel<<<8 * 128, 256, 0, stream>>>(fin, gpart);
            gsum_kernel<<<(8 * 2048) / 256, 256, 0, stream>>>(gpart, gsb, 8 * 2048);
            scan_kernel<<<1, 64, 0, stream>>>(gsb, phase, 8);
            fft512_kernel<<<8 * 512, 256, 0, stream>>>(fin, phase, out3r, nullptr, 0, 1);
        } else {
            // two batch-half passes; fin in out0 region; gram scratch in out3 tail
            float2* fin   = (float2*)out0r;
            float2* o3f2  = (float2*)out3r;
            float2* gpart = o3f2 + (8388608 - 262144 - 8192 - 1024);
            float2* gsb   = o3f2 + (8388608 - 8192 - 1024);
            float2* phase = o3f2 + (8388608 - 1024);
            for (int p = 0; p < 2; p++) {
                int b0 = p * 4;
                ifft4096_kernel<<<4 * NC, 256, 0, stream>>>(xr, xi, fin, b0, 3, 2);
                gram_kernel<<<4 * 128, 256, 0, stream>>>(fin, gpart);
                gsum_kernel<<<(4 * 2048) / 256, 256, 0, stream>>>(gpart, gsb, 4 * 2048);
                scan_kernel<<<1, 64, 0, stream>>>(gsb, phase, 4);
                scale_kernel<<<4 * 2048, 256, 0, stream>>>((float4*)fin, phase, 4 * 524288);
                fft512_kernel<<<4 * 512, 256, 0, stream>>>(fin, nullptr, out3r, nullptr, b0, 1);
            }
        }
        copy_kernel<<<2048, 256, 0, stream>>>((const float4*)xr, (float4*)out0r, 2097152);
    } else {
        // defensive path: complex outputs as float pairs
        float2* out0f2 = (float2*)out;
        float2* out3f2 = (float2*)(out + 16777216);
        float2* fin   = out0f2;
        float2* gpart = out3f2 + (16777216 - 524288 - 16384 - 2048);
        float2* gsb   = out3f2 + (16777216 - 16384 - 2048);
        float2* phase = out3f2 + (16777216 - 2048);
        ifft4096_kernel<<<8 * NC, 256, 0, stream>>>(xr, xi, fin, 0, 7, 3);
        gram_kernel<<<8 * 128, 256, 0, stream>>>(fin, gpart);
        gsum_kernel<<<(8 * 2048) / 256, 256, 0, stream>>>(gpart, gsb, 8 * 2048);
        scan_kernel<<<1, 64, 0, stream>>>(gsb, phase, 8);
        scale_kernel<<<8 * 2048, 256, 0, stream>>>((float4*)fin, phase, 8 * 524288);
        fft512_kernel<<<8 * 512, 256, 0, stream>>>(fin, nullptr, nullptr, out3f2, 0, 0);
        pack_x_kernel<<<4096, 256, 0, stream>>>((const float2*)xr, (const float2*)xi,
                                                (float4*)out0f2, 4194304);
    }
}

// Round 6
// 277.500 us; speedup vs baseline: 1.5784x; 1.1187x over previous
//
#include <hip/hip_runtime.h>
#include <math.h>

#define NF 4096   // ifft length (dot axis)
#define NC 256    // scan axis length
#define NJ 512    // fft output length
#define CH 128    // gram m-chunk size
#define TWO_PI_F 6.28318530717958647692f

__device__ __forceinline__ float2 cmul(float2 a, float2 b) {
    return make_float2(a.x*b.x - a.y*b.y, a.x*b.y + a.y*b.x);
}

// ---------- register DFT primitives (verified with delta inputs) ----------
__device__ __forceinline__ void dft4i(float2& x0, float2& x1, float2& x2, float2& x3, float sgn) {
    float2 t0 = make_float2(x0.x + x2.x, x0.y + x2.y);
    float2 t1 = make_float2(x0.x - x2.x, x0.y - x2.y);
    float2 t2 = make_float2(x1.x + x3.x, x1.y + x3.y);
    float2 t3 = make_float2(x1.x - x3.x, x1.y - x3.y);
    float2 it3 = make_float2(-sgn * t3.y, sgn * t3.x);   // sgn*i*t3
    x0 = make_float2(t0.x + t2.x, t0.y + t2.y);
    x2 = make_float2(t0.x - t2.x, t0.y - t2.y);
    x1 = make_float2(t1.x + it3.x, t1.y + it3.y);
    x3 = make_float2(t1.x - it3.x, t1.y - it3.y);
}

// natural-order DFT16 in registers; v_j ends up in slot 4*(j&3) + (j>>2)
__device__ __forceinline__ void dft16(float2* u, float sgn) {
    dft4i(u[0], u[4], u[8],  u[12], sgn);
    dft4i(u[1], u[5], u[9],  u[13], sgn);
    dft4i(u[2], u[6], u[10], u[14], sgn);
    dft4i(u[3], u[7], u[11], u[15], sgn);
    const float C1 = 0.9238795325112867f, S1 = 0.3826834323650898f, R2 = 0.7071067811865476f;
    u[5]  = cmul(u[5],  make_float2(C1,  sgn * S1));
    u[6]  = cmul(u[6],  make_float2(R2,  sgn * R2));
    u[7]  = cmul(u[7],  make_float2(S1,  sgn * C1));
    u[9]  = cmul(u[9],  make_float2(R2,  sgn * R2));
    u[10] = cmul(u[10], make_float2(0.f, sgn));
    u[11] = cmul(u[11], make_float2(-R2, sgn * R2));
    u[13] = cmul(u[13], make_float2(S1,  sgn * C1));
    u[14] = cmul(u[14], make_float2(-R2, sgn * R2));
    u[15] = cmul(u[15], make_float2(-C1, -sgn * S1));
    dft4i(u[0],  u[1],  u[2],  u[3],  sgn);
    dft4i(u[4],  u[5],  u[6],  u[7],  sgn);
    dft4i(u[8],  u[9],  u[10], u[11], sgn);
    dft4i(u[12], u[13], u[14], u[15], sgn);
}

// natural-order DFT8: out v[0..7] from in u[0..7]
__device__ __forceinline__ void dft8(const float2* u, float2* v, float sgn) {
    float2 e0 = u[0], e1 = u[2], e2 = u[4], e3 = u[6];
    float2 o0 = u[1], o1 = u[3], o2 = u[5], o3 = u[7];
    dft4i(e0, e1, e2, e3, sgn);
    dft4i(o0, o1, o2, o3, sgn);
    const float R2 = 0.7071067811865476f;
    float2 w1 = make_float2(R2, sgn * R2);
    float2 w2 = make_float2(0.f, sgn);
    float2 w3 = make_float2(-R2, sgn * R2);
    float2 t1 = cmul(o1, w1), t2 = cmul(o2, w2), t3 = cmul(o3, w3);
    v[0] = make_float2(e0.x + o0.x, e0.y + o0.y);
    v[4] = make_float2(e0.x - o0.x, e0.y - o0.y);
    v[1] = make_float2(e1.x + t1.x, e1.y + t1.y);
    v[5] = make_float2(e1.x - t1.x, e1.y - t1.y);
    v[2] = make_float2(e2.x + t2.x, e2.y + t2.y);
    v[6] = make_float2(e2.x - t2.x, e2.y - t2.y);
    v[3] = make_float2(e3.x + t3.x, e3.y + t3.y);
    v[7] = make_float2(e3.x - t3.x, e3.y - t3.y);
}

// ---------------- stage A: transpose x[b,f,c] -> fin[b,c,f] (scaled), 64x64 LDS tiles ----------------
__global__ __launch_bounds__(256) void transpose_kernel(const float* __restrict__ xr,
                                                        const float* __restrict__ xi,
                                                        float2* __restrict__ fin,
                                                        int b0, int nbm1, int nbshift) {
    __shared__ float ldr[64][65];   // odd word stride -> conflict-free both phases
    __shared__ float ldi[64][65];
    int wg = blockIdx.x;
    int bl = wg & nbm1;
    int rest = wg >> nbshift;
    int ft = rest & 63;            // 64 f-tiles
    int ct = rest >> 6;            // 4 c-tiles
    int f0 = ft << 6, c0 = ct << 6;
    int t = threadIdx.x;
    int cl = t & 63;
    int rq = t >> 6;               // 0..3
    const float scale = 1.0f / (4096.0f * 1.5f);
    int bg = b0 + bl;
    const float* xrb = xr + (size_t)bg * NF * NC;
    const float* xib = xi + (size_t)bg * NF * NC;
#pragma unroll
    for (int q = 0; q < 16; q++) {
        int r = q * 4 + rq;        // f-row in tile
        size_t idx = (size_t)(f0 + r) * NC + c0 + cl;   // consecutive cl -> coalesced
        ldr[cl][r] = xrb[idx] * scale;
        ldi[cl][r] = xib[idx] * scale;
    }
    __syncthreads();
    int fl = t & 63;
#pragma unroll
    for (int q = 0; q < 16; q++) {
        int cr = q * 4 + rq;       // c-row in tile
        fin[((size_t)(bl * NC + c0 + cr)) * NF + f0 + fl] =
            make_float2(ldr[cr][fl], ldi[cr][fl]);      // consecutive fl -> coalesced
    }
}

// ---------------- stage B: IFFT-4096 in place over fin[b,c,:], Stockham radix-16 ----------------
#define IPAD(a) ((a) + ((a) >> 4))

template<int P>
__device__ __forceinline__ void pass16(float2* S, int t, float sgn) {
    const int k = t & (P - 1);
    float2 u[16];
#pragma unroll
    for (int r = 0; r < 16; r++) u[r] = S[IPAD(t + 256 * r)];
    __syncthreads();
    if (P > 1) {
        float ab = sgn * (TWO_PI_F / (16.0f * (float)P)) * (float)k;
#pragma unroll
        for (int r = 1; r < 16; r++) {
            float sn, cs; __sincosf(ab * (float)r, &sn, &cs);
            u[r] = cmul(u[r], make_float2(cs, sn));
        }
    }
    dft16(u, sgn);
    const int base = 16 * P * (t / P) + k;
#pragma unroll
    for (int j = 0; j < 16; j++) {
        const int sl = ((j & 3) << 2) | (j >> 2);
        S[IPAD(base + j * P)] = u[sl];
    }
    __syncthreads();
}

__global__ __launch_bounds__(256) void ifft4096_kernel(float2* __restrict__ fin,
                                                       int bmask, int bshift) {
    __shared__ float2 S[4352];   // 34 KiB
    int wg = blockIdx.x;
    int bl = wg & bmask;
    int c = wg >> bshift;
    int t = threadIdx.x;
    size_t base = ((size_t)(bl * NC + c)) * NF;
#pragma unroll
    for (int q = 0; q < 16; q++) {
        int f = t + 256 * q;
        S[IPAD(f)] = fin[base + f];    // coalesced 8B/lane
    }
    __syncthreads();
    pass16<1>(S, t, 1.0f);
    pass16<16>(S, t, 1.0f);
    pass16<256>(S, t, 1.0f);
#pragma unroll
    for (int q = 0; q < 16; q++) {
        int f = t + 256 * q;
        fin[base + f] = S[IPAD(f)];
    }
}

// ---------------- stage C1: banded Gram partials, k-segmented ----------------
__global__ __launch_bounds__(256) void gram_kernel(const float2* __restrict__ fin,
                                                   float2* __restrict__ gpart) {
    __shared__ float2 ring[16][CH];
    int wg = blockIdx.x;            // bl*128 + ch*4 + ks
    int bl = wg >> 7;
    int ch = (wg >> 2) & 31;
    int ks = wg & 3;
    int m0 = ch * CH;
    int k0 = ks * 64;
    int kend = k0 + 64;
    int t = threadIdx.x;
    int dgrp = t >> 5;              // 0..7 -> d = dgrp+1
    int lane = t & 31;
    for (int r = (k0 >= 8 ? k0 - 8 : 0); r <= k0; r++)
        if (t < CH) ring[r & 15][t] = fin[((size_t)(bl * NC + r)) * NF + m0 + t];
    __syncthreads();
    for (int k = k0; k < kend; k++) {
        float2 nxt;
        bool ld = (k + 1 < kend) && (t < CH);
        if (ld) nxt = fin[((size_t)(bl * NC + k + 1)) * NF + m0 + t];
        int d = dgrp + 1;
        float2 acc = make_float2(0.f, 0.f);
        if (k - d >= 0) {
            int sk = k & 15, sj = (k - d) & 15;
#pragma unroll
            for (int i = 0; i < 4; i++) {
                int m = lane + 32 * i;
                float2 a = ring[sj][m];
                float2 bb = ring[sk][m];
                acc.x += a.x * bb.x + a.y * bb.y;
                acc.y += a.x * bb.y - a.y * bb.x;
            }
        }
#pragma unroll
        for (int off = 16; off >= 1; off >>= 1) {
            acc.x += __shfl_xor(acc.x, off);
            acc.y += __shfl_xor(acc.y, off);
        }
        if (lane == 0)
            gpart[((size_t)(bl * 32 + ch) * NC + k) * 8 + dgrp] = acc;
        if (ld) ring[(k + 1) & 15][t] = nxt;
        __syncthreads();
    }
}

// ---------------- stage C2a: sum Gram partials over 32 chunks ----------------
__global__ void gsum_kernel(const float2* __restrict__ gpart, float2* __restrict__ gs, int total) {
    int e = blockIdx.x * blockDim.x + threadIdx.x;
    if (e >= total) return;
    int bl = e >> 11;
    int kd = e & 2047;
    float2 s = make_float2(0.f, 0.f);
    for (int ch = 0; ch < 32; ch++) {
        float2 v = gpart[((size_t)(bl * 32 + ch)) * 2048 + kd];
        s.x += v.x; s.y += v.y;
    }
    gs[e] = s;
}

// ---------------- stage C2b: scalar phase recurrence ----------------
__global__ void scan_kernel(const float2* __restrict__ gs, float2* __restrict__ phase, int nb) {
    int bl = threadIdx.x;
    if (bl >= nb) return;
    float2 p1 = make_float2(1.f, 0.f);
    float2 z = make_float2(0.f, 0.f);
    float2 p2 = z, p3 = z, p4 = z, p5 = z, p6 = z, p7 = z, p8 = z;
    phase[bl * NC] = p1;
    for (int k = 1; k < NC; k++) {
        const float2* g = &gs[((size_t)bl * NC + k) * 8];
        float2 g0 = g[0], g1 = g[1], g2 = g[2], g3 = g[3];
        float2 g4 = g[4], g5 = g[5], g6 = g[6], g7 = g[7];
        float2 s = make_float2(0.f, 0.f);
        s.x += p1.x*g0.x - p1.y*g0.y; s.y += p1.x*g0.y + p1.y*g0.x;
        s.x += p2.x*g1.x - p2.y*g1.y; s.y += p2.x*g1.y + p2.y*g1.x;
        s.x += p3.x*g2.x - p3.y*g2.y; s.y += p3.x*g2.y + p3.y*g2.x;
        s.x += p4.x*g3.x - p4.y*g3.y; s.y += p4.x*g3.y + p4.y*g3.x;
        s.x += p5.x*g4.x - p5.y*g4.y; s.y += p5.x*g4.y + p5.y*g4.x;
        s.x += p6.x*g5.x - p6.y*g5.y; s.y += p6.x*g5.y + p6.y*g5.x;
        s.x += p7.x*g6.x - p7.y*g6.y; s.y += p7.x*g6.y + p7.y*g6.x;
        s.x += p8.x*g7.x - p8.y*g7.y; s.y += p8.x*g7.y + p8.y*g7.x;
        float inv = 1.0f / sqrtf(s.x * s.x + s.y * s.y);
        float2 np = make_float2(s.x * inv, s.y * inv);
        phase[bl * NC + k] = np;
        p8 = p7; p7 = p6; p6 = p5; p5 = p4; p4 = p3; p3 = p2; p2 = p1; p1 = np;
    }
}

// ---------------- stage C3 (fallback paths only): fin *= conj(phase) ----------------
__global__ void scale_kernel(float4* __restrict__ fin4, const float2* __restrict__ phase, int n4) {
    int i = blockIdx.x * blockDim.x + threadIdx.x;
    if (i >= n4) return;
    int row = i >> 11;
    float2 ph = phase[row];
    float4 v = fin4[i];
    fin4[i] = make_float4(v.x*ph.x + v.y*ph.y, v.y*ph.x - v.x*ph.y,
                          v.z*ph.x + v.w*ph.y, v.w*ph.x - v.z*ph.y);
}

// ---------------- stage D: FFT-512 over c (zero-padded), Stockham radix-8, fused conj(phase) ----------------
#define FPAD 516   // row stride (float2) for [8][516] LDS

template<int P, bool ZTOP>
__device__ __forceinline__ void pass8x(float2* L, int fp, int i2, float sgn) {
    const int ia = i2, ib = i2 + 32;
    const int ka = ia & (P - 1), kb = ib & (P - 1);
    float2 ua[8], ub[8];
#pragma unroll
    for (int r = 0; r < 8; r++) {
        if (ZTOP && r >= 4) {
            ua[r] = make_float2(0.f, 0.f);
            ub[r] = make_float2(0.f, 0.f);
        } else {
            ua[r] = L[fp * FPAD + ia + 64 * r];
            ub[r] = L[fp * FPAD + ib + 64 * r];
        }
    }
    __syncthreads();
    if (P > 1) {
        float aba = sgn * (TWO_PI_F / (8.0f * (float)P)) * (float)ka;
        float abb = sgn * (TWO_PI_F / (8.0f * (float)P)) * (float)kb;
#pragma unroll
        for (int r = 1; r < 8; r++) {
            float sn, cs;
            __sincosf(aba * (float)r, &sn, &cs);
            ua[r] = cmul(ua[r], make_float2(cs, sn));
            __sincosf(abb * (float)r, &sn, &cs);
            ub[r] = cmul(ub[r], make_float2(cs, sn));
        }
    }
    float2 va[8], vb[8];
    dft8(ua, va, sgn);
    dft8(ub, vb, sgn);
    const int basea = 8 * P * (ia / P) + ka;
    const int baseb = 8 * P * (ib / P) + kb;
#pragma unroll
    for (int r = 0; r < 8; r++) {
        L[fp * FPAD + basea + r * P] = va[r];
        L[fp * FPAD + baseb + r * P] = vb[r];
    }
    __syncthreads();
}

__global__ __launch_bounds__(256) void fft512_kernel(const float2* __restrict__ fin,
                                                     const float2* __restrict__ ph,   // may be null
                                                     float* __restrict__ outr,
                                                     float2* __restrict__ outc,
                                                     int b0, int realOnly) {
    __shared__ float2 L[8 * FPAD];   // 33 KiB
    int wg = blockIdx.x;             // bl*512 + ftile
    int bl = wg >> 9;
    int f0 = (wg & 511) * 8;
    int t = threadIdx.x;
    int fpp = t & 7;
    int cg = t >> 3;                 // 0..31
#pragma unroll
    for (int it = 0; it < 8; it++) {
        int c = it * 32 + cg;
        float2 v = fin[((size_t)(bl * NC + c)) * NF + f0 + fpp];
        if (ph) {
            float2 p = ph[bl * NC + c];
            v = make_float2(v.x * p.x + v.y * p.y, v.y * p.x - v.x * p.y);  // f*conj(ph)
        }
        L[fpp * FPAD + c] = v;
    }
    __syncthreads();
    int fp = t & 7;
    int i2 = t >> 3;                 // 0..31
    pass8x<1, true >(L, fp, i2, -1.0f);
    pass8x<8, false>(L, fp, i2, -1.0f);
    pass8x<64, false>(L, fp, i2, -1.0f);
    size_t ob = ((size_t)((b0 + bl) * NF + f0)) * NJ;
    if (realOnly) {
#pragma unroll
        for (int fp2 = 0; fp2 < 8; fp2++)
#pragma unroll
            for (int jq = 0; jq < 2; jq++) {
                int j = t + 256 * jq;
                outr[ob + (size_t)fp2 * NJ + j] = L[fp2 * FPAD + j].x;
            }
    } else {
#pragma unroll
        for (int fp2 = 0; fp2 < 8; fp2++)
#pragma unroll
            for (int jq = 0; jq < 2; jq++) {
                int j = t + 256 * jq;
                outc[ob + (size_t)fp2 * NJ + j] = L[fp2 * FPAD + j];
            }
    }
}

// ---------------- output 0 writers (run LAST) ----------------
__global__ void copy_kernel(const float4* __restrict__ src, float4* __restrict__ dst, int n4) {
    int i = blockIdx.x * blockDim.x + threadIdx.x;
    int stride = gridDim.x * blockDim.x;
    for (; i < n4; i += stride) dst[i] = src[i];
}
__global__ void pack_x_kernel(const float2* __restrict__ xr, const float2* __restrict__ xi,
                              float4* __restrict__ out, int n4) {
    int i = blockIdx.x * blockDim.x + threadIdx.x;
    int stride = gridDim.x * blockDim.x;
    for (; i < n4; i += stride) {
        float2 r = xr[i], m = xi[i];
        out[i] = make_float4(r.x, m.x, r.y, m.y);
    }
}

extern "C" void kernel_launch(void* const* d_in, const int* in_sizes, int n_in,
                              void* d_out, int out_size, void* d_ws, size_t ws_size,
                              hipStream_t stream) {
    const float* xr = (const float*)d_in[0];
    const float* xi = (const float*)d_in[1];
    float* out = (float*)d_out;

    if (out_size < 40000000) {
        // real-only outputs: out0 = x_real (8388608 f), out3 = Re(out3) (16777216 f)
        float* out0r = out;
        float* out3r = out + 8388608;
        size_t need = (size_t)(8388608 + 524288 + 16384 + 2048) * sizeof(float2);
        if (ws_size >= need) {
            float2* fin   = (float2*)d_ws;
            float2* gpart = fin + 8388608;
            float2* gsb   = gpart + 524288;
            float2* phase = gsb + 16384;
            transpose_kernel<<<8 * 256, 256, 0, stream>>>(xr, xi, fin, 0, 7, 3);
            ifft4096_kernel<<<8 * NC, 256, 0, stream>>>(fin, 7, 3);
            gram_kernel<<<8 * 128, 256, 0, stream>>>(fin, gpart);
            gsum_kernel<<<(8 * 2048) / 256, 256, 0, stream>>>(gpart, gsb, 8 * 2048);
            scan_kernel<<<1, 64, 0, stream>>>(gsb, phase, 8);
            fft512_kernel<<<8 * 512, 256, 0, stream>>>(fin, phase, out3r, nullptr, 0, 1);
        } else {
            // two batch-half passes; fin in out0 region; gram scratch in out3 tail
            float2* fin   = (float2*)out0r;
            float2* o3f2  = (float2*)out3r;
            float2* gpart = o3f2 + (8388608 - 262144 - 8192 - 1024);
            float2* gsb   = o3f2 + (8388608 - 8192 - 1024);
            float2* phase = o3f2 + (8388608 - 1024);
            for (int p = 0; p < 2; p++) {
                int b0 = p * 4;
                transpose_kernel<<<4 * 256, 256, 0, stream>>>(xr, xi, fin, b0, 3, 2);
                ifft4096_kernel<<<4 * NC, 256, 0, stream>>>(fin, 3, 2);
                gram_kernel<<<4 * 128, 256, 0, stream>>>(fin, gpart);
                gsum_kernel<<<(4 * 2048) / 256, 256, 0, stream>>>(gpart, gsb, 4 * 2048);
                scan_kernel<<<1, 64, 0, stream>>>(gsb, phase, 4);
                scale_kernel<<<4 * 2048, 256, 0, stream>>>((float4*)fin, phase, 4 * 524288);
                fft512_kernel<<<4 * 512, 256, 0, stream>>>(fin, nullptr, out3r, nullptr, b0, 1);
            }
        }
        copy_kernel<<<2048, 256, 0, stream>>>((const float4*)xr, (float4*)out0r, 2097152);
    } else {
        // defensive path: complex outputs as float pairs
        float2* out0f2 = (float2*)out;
        float2* out3f2 = (float2*)(out + 16777216);
        float2* fin   = out0f2;
        float2* gpart = out3f2 + (16777216 - 524288 - 16384 - 2048);
        float2* gsb   = out3f2 + (16777216 - 16384 - 2048);
        float2* phase = out3f2 + (16777216 - 2048);
        transpose_kernel<<<8 * 256, 256, 0, stream>>>(xr, xi, fin, 0, 7, 3);
        ifft4096_kernel<<<8 * NC, 256, 0, stream>>>(fin, 7, 3);
        gram_kernel<<<8 * 128, 256, 0, stream>>>(fin, gpart);
        gsum_kernel<<<(8 * 2048) / 256, 256, 0, stream>>>(gpart, gsb, 8 * 2048);
        scan_kernel<<<1, 64, 0, stream>>>(gsb, phase, 8);
        scale_kernel<<<8 * 2048, 256, 0, stream>>>((float4*)fin, phase, 8 * 524288);
        fft512_kernel<<<8 * 512, 256, 0, stream>>>(fin, nullptr, nullptr, out3f2, 0, 0);
        pack_x_kernel<<<4096, 256, 0, stream>>>((const float2*)xr, (const float2*)xi,
                                                (float4*)out0f2, 4194304);
    }
}

// Round 7
// 270.247 us; speedup vs baseline: 1.6208x; 1.0268x over previous
//
#include <hip/hip_runtime.h>
#include <math.h>

#define NF 4096   // ifft length (dot axis)
#define NC 256    // scan axis length
#define NJ 512    // fft output length
#define CH 128    // gram m-chunk size
#define TWO_PI_F 6.28318530717958647692f

__device__ __forceinline__ float2 cmul(float2 a, float2 b) {
    return make_float2(a.x*b.x - a.y*b.y, a.x*b.y + a.y*b.x);
}

// ---------- register DFT primitives (verified with delta inputs) ----------
__device__ __forceinline__ void dft4i(float2& x0, float2& x1, float2& x2, float2& x3, float sgn) {
    float2 t0 = make_float2(x0.x + x2.x, x0.y + x2.y);
    float2 t1 = make_float2(x0.x - x2.x, x0.y - x2.y);
    float2 t2 = make_float2(x1.x + x3.x, x1.y + x3.y);
    float2 t3 = make_float2(x1.x - x3.x, x1.y - x3.y);
    float2 it3 = make_float2(-sgn * t3.y, sgn * t3.x);   // sgn*i*t3
    x0 = make_float2(t0.x + t2.x, t0.y + t2.y);
    x2 = make_float2(t0.x - t2.x, t0.y - t2.y);
    x1 = make_float2(t1.x + it3.x, t1.y + it3.y);
    x3 = make_float2(t1.x - it3.x, t1.y - it3.y);
}

// natural-order DFT16 in registers; v_j ends up in slot 4*(j&3) + (j>>2)
__device__ __forceinline__ void dft16(float2* u, float sgn) {
    dft4i(u[0], u[4], u[8],  u[12], sgn);
    dft4i(u[1], u[5], u[9],  u[13], sgn);
    dft4i(u[2], u[6], u[10], u[14], sgn);
    dft4i(u[3], u[7], u[11], u[15], sgn);
    const float C1 = 0.9238795325112867f, S1 = 0.3826834323650898f, R2 = 0.7071067811865476f;
    u[5]  = cmul(u[5],  make_float2(C1,  sgn * S1));
    u[6]  = cmul(u[6],  make_float2(R2,  sgn * R2));
    u[7]  = cmul(u[7],  make_float2(S1,  sgn * C1));
    u[9]  = cmul(u[9],  make_float2(R2,  sgn * R2));
    u[10] = cmul(u[10], make_float2(0.f, sgn));
    u[11] = cmul(u[11], make_float2(-R2, sgn * R2));
    u[13] = cmul(u[13], make_float2(S1,  sgn * C1));
    u[14] = cmul(u[14], make_float2(-R2, sgn * R2));
    u[15] = cmul(u[15], make_float2(-C1, -sgn * S1));
    dft4i(u[0],  u[1],  u[2],  u[3],  sgn);
    dft4i(u[4],  u[5],  u[6],  u[7],  sgn);
    dft4i(u[8],  u[9],  u[10], u[11], sgn);
    dft4i(u[12], u[13], u[14], u[15], sgn);
}

// natural-order DFT8: out v[0..7] from in u[0..7]
__device__ __forceinline__ void dft8(const float2* u, float2* v, float sgn) {
    float2 e0 = u[0], e1 = u[2], e2 = u[4], e3 = u[6];
    float2 o0 = u[1], o1 = u[3], o2 = u[5], o3 = u[7];
    dft4i(e0, e1, e2, e3, sgn);
    dft4i(o0, o1, o2, o3, sgn);
    const float R2 = 0.7071067811865476f;
    float2 w1 = make_float2(R2, sgn * R2);
    float2 w2 = make_float2(0.f, sgn);
    float2 w3 = make_float2(-R2, sgn * R2);
    float2 t1 = cmul(o1, w1), t2 = cmul(o2, w2), t3 = cmul(o3, w3);
    v[0] = make_float2(e0.x + o0.x, e0.y + o0.y);
    v[4] = make_float2(e0.x - o0.x, e0.y - o0.y);
    v[1] = make_float2(e1.x + t1.x, e1.y + t1.y);
    v[5] = make_float2(e1.x - t1.x, e1.y - t1.y);
    v[2] = make_float2(e2.x + t2.x, e2.y + t2.y);
    v[6] = make_float2(e2.x - t2.x, e2.y - t2.y);
    v[3] = make_float2(e3.x + t3.x, e3.y + t3.y);
    v[7] = make_float2(e3.x - t3.x, e3.y - t3.y);
}

// ---------------- stage A: transpose x[b,f,c] -> fin[b,c,f] (scaled), 64x64 LDS tiles ----------------
__global__ __launch_bounds__(256) void transpose_kernel(const float* __restrict__ xr,
                                                        const float* __restrict__ xi,
                                                        float2* __restrict__ fin,
                                                        int b0, int nbm1, int nbshift) {
    __shared__ float ldr[64][65];   // odd word stride -> conflict-free both phases
    __shared__ float ldi[64][65];
    int wg = blockIdx.x;
    int bl = wg & nbm1;
    int rest = wg >> nbshift;
    int ft = rest & 63;            // 64 f-tiles
    int ct = rest >> 6;            // 4 c-tiles
    int f0 = ft << 6, c0 = ct << 6;
    int t = threadIdx.x;
    int cl = t & 63;
    int rq = t >> 6;               // 0..3
    const float scale = 1.0f / (4096.0f * 1.5f);
    int bg = b0 + bl;
    const float* xrb = xr + (size_t)bg * NF * NC;
    const float* xib = xi + (size_t)bg * NF * NC;
#pragma unroll
    for (int q = 0; q < 16; q++) {
        int r = q * 4 + rq;        // f-row in tile
        size_t idx = (size_t)(f0 + r) * NC + c0 + cl;   // consecutive cl -> coalesced
        ldr[cl][r] = xrb[idx] * scale;
        ldi[cl][r] = xib[idx] * scale;
    }
    __syncthreads();
    int fl = t & 63;
#pragma unroll
    for (int q = 0; q < 16; q++) {
        int cr = q * 4 + rq;       // c-row in tile
        fin[((size_t)(bl * NC + c0 + cr)) * NF + f0 + fl] =
            make_float2(ldr[cr][fl], ldi[cr][fl]);      // consecutive fl -> coalesced
    }
}

// ---------------- stage B: IFFT-4096 in place over fin[b,c,:], Stockham radix-16 ----------------
#define IPAD(a) ((a) + ((a) >> 4))

template<int P>
__device__ __forceinline__ void pass16(float2* S, int t, float sgn) {
    const int k = t & (P - 1);
    float2 u[16];
#pragma unroll
    for (int r = 0; r < 16; r++) u[r] = S[IPAD(t + 256 * r)];
    __syncthreads();
    if (P > 1) {
        float ab = sgn * (TWO_PI_F / (16.0f * (float)P)) * (float)k;
#pragma unroll
        for (int r = 1; r < 16; r++) {
            float sn, cs; __sincosf(ab * (float)r, &sn, &cs);
            u[r] = cmul(u[r], make_float2(cs, sn));
        }
    }
    dft16(u, sgn);
    const int base = 16 * P * (t / P) + k;
#pragma unroll
    for (int j = 0; j < 16; j++) {
        const int sl = ((j & 3) << 2) | (j >> 2);
        S[IPAD(base + j * P)] = u[sl];
    }
    __syncthreads();
}

__global__ __launch_bounds__(256) void ifft4096_kernel(float2* __restrict__ fin,
                                                       int bmask, int bshift) {
    __shared__ float2 S[4352];   // 34 KiB
    int wg = blockIdx.x;
    int bl = wg & bmask;
    int c = wg >> bshift;
    int t = threadIdx.x;
    size_t base = ((size_t)(bl * NC + c)) * NF;
#pragma unroll
    for (int q = 0; q < 16; q++) {
        int f = t + 256 * q;
        S[IPAD(f)] = fin[base + f];    // coalesced 8B/lane
    }
    __syncthreads();
    pass16<1>(S, t, 1.0f);
    pass16<16>(S, t, 1.0f);
    pass16<256>(S, t, 1.0f);
#pragma unroll
    for (int q = 0; q < 16; q++) {
        int f = t + 256 * q;
        fin[base + f] = S[IPAD(f)];
    }
}

// ---------------- stage C1: banded Gram partials, k-segmented ----------------
__global__ __launch_bounds__(256) void gram_kernel(const float2* __restrict__ fin,
                                                   float2* __restrict__ gpart) {
    __shared__ float2 ring[16][CH];
    int wg = blockIdx.x;            // bl*128 + ch*4 + ks
    int bl = wg >> 7;
    int ch = (wg >> 2) & 31;
    int ks = wg & 3;
    int m0 = ch * CH;
    int k0 = ks * 64;
    int kend = k0 + 64;
    int t = threadIdx.x;
    int dgrp = t >> 5;              // 0..7 -> d = dgrp+1
    int lane = t & 31;
    for (int r = (k0 >= 8 ? k0 - 8 : 0); r <= k0; r++)
        if (t < CH) ring[r & 15][t] = fin[((size_t)(bl * NC + r)) * NF + m0 + t];
    __syncthreads();
    for (int k = k0; k < kend; k++) {
        float2 nxt;
        bool ld = (k + 1 < kend) && (t < CH);
        if (ld) nxt = fin[((size_t)(bl * NC + k + 1)) * NF + m0 + t];
        int d = dgrp + 1;
        float2 acc = make_float2(0.f, 0.f);
        if (k - d >= 0) {
            int sk = k & 15, sj = (k - d) & 15;
#pragma unroll
            for (int i = 0; i < 4; i++) {
                int m = lane + 32 * i;
                float2 a = ring[sj][m];
                float2 bb = ring[sk][m];
                acc.x += a.x * bb.x + a.y * bb.y;
                acc.y += a.x * bb.y - a.y * bb.x;
            }
        }
#pragma unroll
        for (int off = 16; off >= 1; off >>= 1) {
            acc.x += __shfl_xor(acc.x, off);
            acc.y += __shfl_xor(acc.y, off);
        }
        if (lane == 0)
            gpart[((size_t)(bl * 32 + ch) * NC + k) * 8 + dgrp] = acc;
        if (ld) ring[(k + 1) & 15][t] = nxt;
        __syncthreads();
    }
}

// ---------------- stage C2a: sum Gram partials over 32 chunks ----------------
__global__ void gsum_kernel(const float2* __restrict__ gpart, float2* __restrict__ gs, int total) {
    int e = blockIdx.x * blockDim.x + threadIdx.x;
    if (e >= total) return;
    int bl = e >> 11;
    int kd = e & 2047;
    float2 s = make_float2(0.f, 0.f);
    for (int ch = 0; ch < 32; ch++) {
        float2 v = gpart[((size_t)(bl * 32 + ch)) * 2048 + kd];
        s.x += v.x; s.y += v.y;
    }
    gs[e] = s;
}

// ---------------- stage C2b: scalar phase recurrence, LDS-staged ----------------
// gsum layout per batch: 2048 float2 (256 k x 8 d). Stage 64-k chunks into LDS with
// per-batch stride 514 (4*t mod 32 -> 8 active lanes hit 8 distinct banks).
#define BSTR 514
__global__ __launch_bounds__(64) void scan_kernel(const float2* __restrict__ gs,
                                                  float2* __restrict__ phase, int nb) {
    __shared__ float2 lg[8 * BSTR];   // 32.2 KiB
    int t = threadIdx.x;
    float2 z = make_float2(0.f, 0.f);
    float2 p1 = make_float2(1.f, 0.f);
    float2 p2 = z, p3 = z, p4 = z, p5 = z, p6 = z, p7 = z, p8 = z;
    if (t < nb) phase[t * NC] = p1;
    for (int c = 0; c < 4; c++) {
        // cooperative load of chunk c: 64 k-steps x 8 d x nb batches
#pragma unroll
        for (int i = 0; i < 64; i++) {
            int e = t + 64 * i;          // bl = e>>9, rem = e&511 (kk*8+d)
            int bl = e >> 9;
            if (bl < nb)
                lg[bl * BSTR + (e & 511)] = gs[(size_t)bl * 2048 + c * 512 + (e & 511)];
        }
        __syncthreads();
        if (t < nb) {
            const float2* lgb = &lg[t * BSTR];
            int kk0 = (c == 0) ? 1 : 0;
#pragma unroll 8
            for (int kk = kk0; kk < 64; kk++) {
                const float2* g = &lgb[kk * 8];
                float2 g0 = g[0], g1 = g[1], g2 = g[2], g3 = g[3];
                float2 g4 = g[4], g5 = g[5], g6 = g[6], g7 = g[7];
                float2 s = z;
                s.x += p1.x*g0.x - p1.y*g0.y; s.y += p1.x*g0.y + p1.y*g0.x;
                s.x += p2.x*g1.x - p2.y*g1.y; s.y += p2.x*g1.y + p2.y*g1.x;
                s.x += p3.x*g2.x - p3.y*g2.y; s.y += p3.x*g2.y + p3.y*g2.x;
                s.x += p4.x*g3.x - p4.y*g3.y; s.y += p4.x*g3.y + p4.y*g3.x;
                s.x += p5.x*g4.x - p5.y*g4.y; s.y += p5.x*g4.y + p5.y*g4.x;
                s.x += p6.x*g5.x - p6.y*g5.y; s.y += p6.x*g5.y + p6.y*g5.x;
                s.x += p7.x*g6.x - p7.y*g6.y; s.y += p7.x*g6.y + p7.y*g6.x;
                s.x += p8.x*g7.x - p8.y*g7.y; s.y += p8.x*g7.y + p8.y*g7.x;
                float inv = 1.0f / sqrtf(s.x * s.x + s.y * s.y);
                float2 np = make_float2(s.x * inv, s.y * inv);
                phase[t * NC + c * 64 + kk] = np;
                p8 = p7; p7 = p6; p6 = p5; p5 = p4; p4 = p3; p3 = p2; p2 = p1; p1 = np;
            }
        }
        __syncthreads();
    }
}

// ---------------- stage C3 (fallback paths only): fin *= conj(phase) ----------------
__global__ void scale_kernel(float4* __restrict__ fin4, const float2* __restrict__ phase, int n4) {
    int i = blockIdx.x * blockDim.x + threadIdx.x;
    if (i >= n4) return;
    int row = i >> 11;
    float2 ph = phase[row];
    float4 v = fin4[i];
    fin4[i] = make_float4(v.x*ph.x + v.y*ph.y, v.y*ph.x - v.x*ph.y,
                          v.z*ph.x + v.w*ph.y, v.w*ph.x - v.z*ph.y);
}

// ---------------- stage D: FFT-512 over c (zero-padded), Stockham radix-8, fused conj(phase) ----------------
#define FPAD 516   // row stride (float2) for [8][516] LDS

template<int P, bool ZTOP>
__device__ __forceinline__ void pass8x(float2* L, int fp, int i2, float sgn) {
    const int ia = i2, ib = i2 + 32;
    const int ka = ia & (P - 1), kb = ib & (P - 1);
    float2 ua[8], ub[8];
#pragma unroll
    for (int r = 0; r < 8; r++) {
        if (ZTOP && r >= 4) {
            ua[r] = make_float2(0.f, 0.f);
            ub[r] = make_float2(0.f, 0.f);
        } else {
            ua[r] = L[fp * FPAD + ia + 64 * r];
            ub[r] = L[fp * FPAD + ib + 64 * r];
        }
    }
    __syncthreads();
    if (P > 1) {
        float aba = sgn * (TWO_PI_F / (8.0f * (float)P)) * (float)ka;
        float abb = sgn * (TWO_PI_F / (8.0f * (float)P)) * (float)kb;
#pragma unroll
        for (int r = 1; r < 8; r++) {
            float sn, cs;
            __sincosf(aba * (float)r, &sn, &cs);
            ua[r] = cmul(ua[r], make_float2(cs, sn));
            __sincosf(abb * (float)r, &sn, &cs);
            ub[r] = cmul(ub[r], make_float2(cs, sn));
        }
    }
    float2 va[8], vb[8];
    dft8(ua, va, sgn);
    dft8(ub, vb, sgn);
    const int basea = 8 * P * (ia / P) + ka;
    const int baseb = 8 * P * (ib / P) + kb;
#pragma unroll
    for (int r = 0; r < 8; r++) {
        L[fp * FPAD + basea + r * P] = va[r];
        L[fp * FPAD + baseb + r * P] = vb[r];
    }
    __syncthreads();
}

__global__ __launch_bounds__(256) void fft512_kernel(const float2* __restrict__ fin,
                                                     const float2* __restrict__ ph,   // may be null
                                                     float* __restrict__ outr,
                                                     float2* __restrict__ outc,
                                                     int b0, int realOnly) {
    __shared__ float2 L[8 * FPAD];   // 33 KiB
    int wg = blockIdx.x;             // bl*512 + ftile
    int bl = wg >> 9;
    int f0 = (wg & 511) * 8;
    int t = threadIdx.x;
    int fpp = t & 7;
    int cg = t >> 3;                 // 0..31
#pragma unroll
    for (int it = 0; it < 8; it++) {
        int c = it * 32 + cg;
        float2 v = fin[((size_t)(bl * NC + c)) * NF + f0 + fpp];
        if (ph) {
            float2 p = ph[bl * NC + c];
            v = make_float2(v.x * p.x + v.y * p.y, v.y * p.x - v.x * p.y);  // f*conj(ph)
        }
        L[fpp * FPAD + c] = v;
    }
    __syncthreads();
    int fp = t & 7;
    int i2 = t >> 3;                 // 0..31
    pass8x<1, true >(L, fp, i2, -1.0f);
    pass8x<8, false>(L, fp, i2, -1.0f);
    pass8x<64, false>(L, fp, i2, -1.0f);
    size_t ob = ((size_t)((b0 + bl) * NF + f0)) * NJ;
    if (realOnly) {
#pragma unroll
        for (int fp2 = 0; fp2 < 8; fp2++)
#pragma unroll
            for (int jq = 0; jq < 2; jq++) {
                int j = t + 256 * jq;
                outr[ob + (size_t)fp2 * NJ + j] = L[fp2 * FPAD + j].x;
            }
    } else {
#pragma unroll
        for (int fp2 = 0; fp2 < 8; fp2++)
#pragma unroll
            for (int jq = 0; jq < 2; jq++) {
                int j = t + 256 * jq;
                outc[ob + (size_t)fp2 * NJ + j] = L[fp2 * FPAD + j];
            }
    }
}

// ---------------- output 0 writers (run LAST) ----------------
__global__ void copy_kernel(const float4* __restrict__ src, float4* __restrict__ dst, int n4) {
    int i = blockIdx.x * blockDim.x + threadIdx.x;
    int stride = gridDim.x * blockDim.x;
    for (; i < n4; i += stride) dst[i] = src[i];
}
__global__ void pack_x_kernel(const float2* __restrict__ xr, const float2* __restrict__ xi,
                              float4* __restrict__ out, int n4) {
    int i = blockIdx.x * blockDim.x + threadIdx.x;
    int stride = gridDim.x * blockDim.x;
    for (; i < n4; i += stride) {
        float2 r = xr[i], m = xi[i];
        out[i] = make_float4(r.x, m.x, r.y, m.y);
    }
}

extern "C" void kernel_launch(void* const* d_in, const int* in_sizes, int n_in,
                              void* d_out, int out_size, void* d_ws, size_t ws_size,
                              hipStream_t stream) {
    const float* xr = (const float*)d_in[0];
    const float* xi = (const float*)d_in[1];
    float* out = (float*)d_out;

    if (out_size < 40000000) {
        // real-only outputs: out0 = x_real (8388608 f), out3 = Re(out3) (16777216 f)
        float* out0r = out;
        float* out3r = out + 8388608;
        size_t need = (size_t)(8388608 + 524288 + 16384 + 2048) * sizeof(float2);
        if (ws_size >= need) {
            float2* fin   = (float2*)d_ws;
            float2* gpart = fin + 8388608;
            float2* gsb   = gpart + 524288;
            float2* phase = gsb + 16384;
            transpose_kernel<<<8 * 256, 256, 0, stream>>>(xr, xi, fin, 0, 7, 3);
            ifft4096_kernel<<<8 * NC, 256, 0, stream>>>(fin, 7, 3);
            gram_kernel<<<8 * 128, 256, 0, stream>>>(fin, gpart);
            gsum_kernel<<<(8 * 2048) / 256, 256, 0, stream>>>(gpart, gsb, 8 * 2048);
            scan_kernel<<<1, 64, 0, stream>>>(gsb, phase, 8);
            fft512_kernel<<<8 * 512, 256, 0, stream>>>(fin, phase, out3r, nullptr, 0, 1);
        } else {
            // two batch-half passes; fin in out0 region; gram scratch in out3 tail
            float2* fin   = (float2*)out0r;
            float2* o3f2  = (float2*)out3r;
            float2* gpart = o3f2 + (8388608 - 262144 - 8192 - 1024);
            float2* gsb   = o3f2 + (8388608 - 8192 - 1024);
            float2* phase = o3f2 + (8388608 - 1024);
            for (int p = 0; p < 2; p++) {
                int b0 = p * 4;
                transpose_kernel<<<4 * 256, 256, 0, stream>>>(xr, xi, fin, b0, 3, 2);
                ifft4096_kernel<<<4 * NC, 256, 0, stream>>>(fin, 3, 2);
                gram_kernel<<<4 * 128, 256, 0, stream>>>(fin, gpart);
                gsum_kernel<<<(4 * 2048) / 256, 256, 0, stream>>>(gpart, gsb, 4 * 2048);
                scan_kernel<<<1, 64, 0, stream>>>(gsb, phase, 4);
                scale_kernel<<<4 * 2048, 256, 0, stream>>>((float4*)fin, phase, 4 * 524288);
                fft512_kernel<<<4 * 512, 256, 0, stream>>>(fin, nullptr, out3r, nullptr, b0, 1);
            }
        }
        copy_kernel<<<2048, 256, 0, stream>>>((const float4*)xr, (float4*)out0r, 2097152);
    } else {
        // defensive path: complex outputs as float pairs
        float2* out0f2 = (float2*)out;
        float2* out3f2 = (float2*)(out + 16777216);
        float2* fin   = out0f2;
        float2* gpart = out3f2 + (16777216 - 524288 - 16384 - 2048);
        float2* gsb   = out3f2 + (16777216 - 16384 - 2048);
        float2* phase = out3f2 + (16777216 - 2048);
        transpose_kernel<<<8 * 256, 256, 0, stream>>>(xr, xi, fin, 0, 7, 3);
        ifft4096_kernel<<<8 * NC, 256, 0, stream>>>(fin, 7, 3);
        gram_kernel<<<8 * 128, 256, 0, stream>>>(fin, gpart);
        gsum_kernel<<<(8 * 2048) / 256, 256, 0, stream>>>(gpart, gsb, 8 * 2048);
        scan_kernel<<<1, 64, 0, stream>>>(gsb, phase, 8);
        scale_kernel<<<8 * 2048, 256, 0, stream>>>((float4*)fin, phase, 8 * 524288);
        fft512_kernel<<<8 * 512, 256, 0, stream>>>(fin, nullptr, nullptr, out3f2, 0, 0);
        pack_x_kernel<<<4096, 256, 0, stream>>>((const float2*)xr, (const float2*)xi,
                                                (float4*)out0f2, 4194304);
    }
}

// Round 8
// 210.201 us; speedup vs baseline: 2.0837x; 1.2857x over previous
//
#include <hip/hip_runtime.h>
#include <math.h>

#define NF 4096   // ifft length (dot axis)
#define NC 256    // scan axis length
#define NJ 512    // fft output length
#define CH 128    // gram m-chunk size
#define TWO_PI_F 6.28318530717958647692f

__device__ __forceinline__ float2 cmul(float2 a, float2 b) {
    return make_float2(a.x*b.x - a.y*b.y, a.x*b.y + a.y*b.x);
}

// ---------- register DFT primitives (verified with delta inputs) ----------
__device__ __forceinline__ void dft4i(float2& x0, float2& x1, float2& x2, float2& x3, float sgn) {
    float2 t0 = make_float2(x0.x + x2.x, x0.y + x2.y);
    float2 t1 = make_float2(x0.x - x2.x, x0.y - x2.y);
    float2 t2 = make_float2(x1.x + x3.x, x1.y + x3.y);
    float2 t3 = make_float2(x1.x - x3.x, x1.y - x3.y);
    float2 it3 = make_float2(-sgn * t3.y, sgn * t3.x);   // sgn*i*t3
    x0 = make_float2(t0.x + t2.x, t0.y + t2.y);
    x2 = make_float2(t0.x - t2.x, t0.y - t2.y);
    x1 = make_float2(t1.x + it3.x, t1.y + it3.y);
    x3 = make_float2(t1.x - it3.x, t1.y - it3.y);
}

// natural-order DFT16 in registers; v_j ends up in slot 4*(j&3) + (j>>2)
__device__ __forceinline__ void dft16(float2* u, float sgn) {
    dft4i(u[0], u[4], u[8],  u[12], sgn);
    dft4i(u[1], u[5], u[9],  u[13], sgn);
    dft4i(u[2], u[6], u[10], u[14], sgn);
    dft4i(u[3], u[7], u[11], u[15], sgn);
    const float C1 = 0.9238795325112867f, S1 = 0.3826834323650898f, R2 = 0.7071067811865476f;
    u[5]  = cmul(u[5],  make_float2(C1,  sgn * S1));
    u[6]  = cmul(u[6],  make_float2(R2,  sgn * R2));
    u[7]  = cmul(u[7],  make_float2(S1,  sgn * C1));
    u[9]  = cmul(u[9],  make_float2(R2,  sgn * R2));
    u[10] = cmul(u[10], make_float2(0.f, sgn));
    u[11] = cmul(u[11], make_float2(-R2, sgn * R2));
    u[13] = cmul(u[13], make_float2(S1,  sgn * C1));
    u[14] = cmul(u[14], make_float2(-R2, sgn * R2));
    u[15] = cmul(u[15], make_float2(-C1, -sgn * S1));
    dft4i(u[0],  u[1],  u[2],  u[3],  sgn);
    dft4i(u[4],  u[5],  u[6],  u[7],  sgn);
    dft4i(u[8],  u[9],  u[10], u[11], sgn);
    dft4i(u[12], u[13], u[14], u[15], sgn);
}

// natural-order DFT8: out v[0..7] from in u[0..7]
__device__ __forceinline__ void dft8(const float2* u, float2* v, float sgn) {
    float2 e0 = u[0], e1 = u[2], e2 = u[4], e3 = u[6];
    float2 o0 = u[1], o1 = u[3], o2 = u[5], o3 = u[7];
    dft4i(e0, e1, e2, e3, sgn);
    dft4i(o0, o1, o2, o3, sgn);
    const float R2 = 0.7071067811865476f;
    float2 w1 = make_float2(R2, sgn * R2);
    float2 w2 = make_float2(0.f, sgn);
    float2 w3 = make_float2(-R2, sgn * R2);
    float2 t1 = cmul(o1, w1), t2 = cmul(o2, w2), t3 = cmul(o3, w3);
    v[0] = make_float2(e0.x + o0.x, e0.y + o0.y);
    v[4] = make_float2(e0.x - o0.x, e0.y - o0.y);
    v[1] = make_float2(e1.x + t1.x, e1.y + t1.y);
    v[5] = make_float2(e1.x - t1.x, e1.y - t1.y);
    v[2] = make_float2(e2.x + t2.x, e2.y + t2.y);
    v[6] = make_float2(e2.x - t2.x, e2.y - t2.y);
    v[3] = make_float2(e3.x + t3.x, e3.y + t3.y);
    v[7] = make_float2(e3.x - t3.x, e3.y - t3.y);
}

// ---------------- stage A: transpose x[b,f,c] -> fin[b,c,f] (scaled), 64x64 LDS tiles ----------------
__global__ __launch_bounds__(256) void transpose_kernel(const float* __restrict__ xr,
                                                        const float* __restrict__ xi,
                                                        float2* __restrict__ fin,
                                                        int b0, int nbm1, int nbshift) {
    __shared__ float ldr[64][65];   // odd word stride -> conflict-free both phases
    __shared__ float ldi[64][65];
    int wg = blockIdx.x;
    int bl = wg & nbm1;
    int rest = wg >> nbshift;
    int ft = rest & 63;            // 64 f-tiles
    int ct = rest >> 6;            // 4 c-tiles
    int f0 = ft << 6, c0 = ct << 6;
    int t = threadIdx.x;
    int cl = t & 63;
    int rq = t >> 6;               // 0..3
    const float scale = 1.0f / (4096.0f * 1.5f);
    int bg = b0 + bl;
    const float* xrb = xr + (size_t)bg * NF * NC;
    const float* xib = xi + (size_t)bg * NF * NC;
#pragma unroll
    for (int q = 0; q < 16; q++) {
        int r = q * 4 + rq;        // f-row in tile
        size_t idx = (size_t)(f0 + r) * NC + c0 + cl;   // consecutive cl -> coalesced
        ldr[cl][r] = xrb[idx] * scale;
        ldi[cl][r] = xib[idx] * scale;
    }
    __syncthreads();
    int fl = t & 63;
#pragma unroll
    for (int q = 0; q < 16; q++) {
        int cr = q * 4 + rq;       // c-row in tile
        fin[((size_t)(bl * NC + c0 + cr)) * NF + f0 + fl] =
            make_float2(ldr[cr][fl], ldi[cr][fl]);      // consecutive fl -> coalesced
    }
}

// ---------------- stage B: IFFT-4096 in place over fin[b,c,:], Stockham radix-16 ----------------
#define IPAD(a) ((a) + ((a) >> 4))

template<int P>
__device__ __forceinline__ void pass16(float2* S, int t, float sgn) {
    const int k = t & (P - 1);
    float2 u[16];
#pragma unroll
    for (int r = 0; r < 16; r++) u[r] = S[IPAD(t + 256 * r)];
    __syncthreads();
    if (P > 1) {
        float ab = sgn * (TWO_PI_F / (16.0f * (float)P)) * (float)k;
#pragma unroll
        for (int r = 1; r < 16; r++) {
            float sn, cs; __sincosf(ab * (float)r, &sn, &cs);
            u[r] = cmul(u[r], make_float2(cs, sn));
        }
    }
    dft16(u, sgn);
    const int base = 16 * P * (t / P) + k;
#pragma unroll
    for (int j = 0; j < 16; j++) {
        const int sl = ((j & 3) << 2) | (j >> 2);
        S[IPAD(base + j * P)] = u[sl];
    }
    __syncthreads();
}

__global__ __launch_bounds__(256) void ifft4096_kernel(float2* __restrict__ fin,
                                                       int bmask, int bshift) {
    __shared__ float2 S[4352];   // 34 KiB
    int wg = blockIdx.x;
    int bl = wg & bmask;
    int c = wg >> bshift;
    int t = threadIdx.x;
    size_t base = ((size_t)(bl * NC + c)) * NF;
#pragma unroll
    for (int q = 0; q < 16; q++) {
        int f = t + 256 * q;
        S[IPAD(f)] = fin[base + f];    // coalesced 8B/lane
    }
    __syncthreads();
    pass16<1>(S, t, 1.0f);
    pass16<16>(S, t, 1.0f);
    pass16<256>(S, t, 1.0f);
#pragma unroll
    for (int q = 0; q < 16; q++) {
        int f = t + 256 * q;
        fin[base + f] = S[IPAD(f)];
    }
}

// ---------------- stage C1: banded Gram partials, k-segmented ----------------
__global__ __launch_bounds__(256) void gram_kernel(const float2* __restrict__ fin,
                                                   float2* __restrict__ gpart) {
    __shared__ float2 ring[16][CH];
    int wg = blockIdx.x;            // bl*128 + ch*4 + ks
    int bl = wg >> 7;
    int ch = (wg >> 2) & 31;
    int ks = wg & 3;
    int m0 = ch * CH;
    int k0 = ks * 64;
    int kend = k0 + 64;
    int t = threadIdx.x;
    int dgrp = t >> 5;              // 0..7 -> d = dgrp+1
    int lane = t & 31;
    for (int r = (k0 >= 8 ? k0 - 8 : 0); r <= k0; r++)
        if (t < CH) ring[r & 15][t] = fin[((size_t)(bl * NC + r)) * NF + m0 + t];
    __syncthreads();
    for (int k = k0; k < kend; k++) {
        float2 nxt;
        bool ld = (k + 1 < kend) && (t < CH);
        if (ld) nxt = fin[((size_t)(bl * NC + k + 1)) * NF + m0 + t];
        int d = dgrp + 1;
        float2 acc = make_float2(0.f, 0.f);
        if (k - d >= 0) {
            int sk = k & 15, sj = (k - d) & 15;
#pragma unroll
            for (int i = 0; i < 4; i++) {
                int m = lane + 32 * i;
                float2 a = ring[sj][m];
                float2 bb = ring[sk][m];
                acc.x += a.x * bb.x + a.y * bb.y;
                acc.y += a.x * bb.y - a.y * bb.x;
            }
        }
#pragma unroll
        for (int off = 16; off >= 1; off >>= 1) {
            acc.x += __shfl_xor(acc.x, off);
            acc.y += __shfl_xor(acc.y, off);
        }
        if (lane == 0)
            gpart[((size_t)(bl * 32 + ch) * NC + k) * 8 + dgrp] = acc;
        if (ld) ring[(k + 1) & 15][t] = nxt;
        __syncthreads();
    }
}

// ---------------- stage C2a: sum Gram partials over 32 chunks ----------------
__global__ void gsum_kernel(const float2* __restrict__ gpart, float2* __restrict__ gs, int total) {
    int e = blockIdx.x * blockDim.x + threadIdx.x;
    if (e >= total) return;
    int bl = e >> 11;
    int kd = e & 2047;
    float2 s = make_float2(0.f, 0.f);
    for (int ch = 0; ch < 32; ch++) {
        float2 v = gpart[((size_t)(bl * 32 + ch)) * 2048 + kd];
        s.x += v.x; s.y += v.y;
    }
    gs[e] = s;
}

// ---------------- stage C2b: scalar phase recurrence, register-pipelined ----------------
// Per-lane (one batch per lane, 8 active): groups of 8 k-steps staged in registers
// (float4 G[8][4] = 8 rows x 8 complex), double-buffered; loads for group g+1 issue
// before computing group g -> ~400 cycles of compute cover the global/L2 latency.
// 8-term complex dot is tree-summed (depth ~5 VALU ops); p-shift renames away under
// full unroll.
#define SCAN_STEP(A0, A1, A2, A3, KIDX)  do {                                  \
    float rx0 = p1.x*A0.x - p1.y*A0.y, ry0 = p1.x*A0.y + p1.y*A0.x;            \
    float rx1 = p2.x*A0.z - p2.y*A0.w, ry1 = p2.x*A0.w + p2.y*A0.z;            \
    float rx2 = p3.x*A1.x - p3.y*A1.y, ry2 = p3.x*A1.y + p3.y*A1.x;            \
    float rx3 = p4.x*A1.z - p4.y*A1.w, ry3 = p4.x*A1.w + p4.y*A1.z;            \
    float rx4 = p5.x*A2.x - p5.y*A2.y, ry4 = p5.x*A2.y + p5.y*A2.x;            \
    float rx5 = p6.x*A2.z - p6.y*A2.w, ry5 = p6.x*A2.w + p6.y*A2.z;            \
    float rx6 = p7.x*A3.x - p7.y*A3.y, ry6 = p7.x*A3.y + p7.y*A3.x;            \
    float rx7 = p8.x*A3.z - p8.y*A3.w, ry7 = p8.x*A3.w + p8.y*A3.z;            \
    float sx = ((rx0 + rx1) + (rx2 + rx3)) + ((rx4 + rx5) + (rx6 + rx7));      \
    float sy = ((ry0 + ry1) + (ry2 + ry3)) + ((ry4 + ry5) + (ry6 + ry7));      \
    float inv = 1.0f / sqrtf(sx * sx + sy * sy);                               \
    float2 np = make_float2(sx * inv, sy * inv);                               \
    phase[t * NC + (KIDX)] = np;                                               \
    p8 = p7; p7 = p6; p6 = p5; p5 = p4; p4 = p3; p3 = p2; p2 = p1; p1 = np;    \
} while (0)

#define SCAN_LOADG(BUF, KBASE)  do {                                           \
    _Pragma("unroll") for (int j = 0; j < 8; j++) {                            \
        _Pragma("unroll") for (int q = 0; q < 4; q++)                          \
            BUF[j][q] = gb4[((KBASE) + j) * 4 + q];                            \
    }                                                                          \
} while (0)

#define SCAN_GRP(BUF, KBASE, FIRST)  do {                                      \
    _Pragma("unroll") for (int j = 0; j < 8; j++) {                            \
        if (FIRST && j == 0) {                                                 \
            phase[t * NC] = make_float2(1.f, 0.f);                             \
        } else {                                                               \
            SCAN_STEP(BUF[j][0], BUF[j][1], BUF[j][2], BUF[j][3], (KBASE) + j);\
        }                                                                      \
    }                                                                          \
} while (0)

__global__ __launch_bounds__(64) void scan_kernel(const float2* __restrict__ gs,
                                                  float2* __restrict__ phase, int nb) {
    int t = threadIdx.x;
    if (t >= nb) return;
    const float4* gb4 = (const float4*)(gs + (size_t)t * 2048);   // 256 rows x 4 float4
    float2 z = make_float2(0.f, 0.f);
    float2 p1 = make_float2(1.f, 0.f);
    float2 p2 = z, p3 = z, p4 = z, p5 = z, p6 = z, p7 = z, p8 = z;
    float4 GA[8][4], GB[8][4];
    SCAN_LOADG(GA, 0);
    // 32 groups of 8 k-steps, unrolled by 2 for static ping-pong indexing
    for (int g2 = 0; g2 < 16; g2++) {
        int k0 = g2 * 16;
        SCAN_LOADG(GB, k0 + 8);
        if (g2 == 0) { SCAN_GRP(GA, k0, true); } else { SCAN_GRP(GA, k0, false); }
        if (g2 < 15) SCAN_LOADG(GA, k0 + 16);
        SCAN_GRP(GB, k0 + 8, false);
    }
}

// ---------------- stage C3 (fallback paths only): fin *= conj(phase) ----------------
__global__ void scale_kernel(float4* __restrict__ fin4, const float2* __restrict__ phase, int n4) {
    int i = blockIdx.x * blockDim.x + threadIdx.x;
    if (i >= n4) return;
    int row = i >> 11;
    float2 ph = phase[row];
    float4 v = fin4[i];
    fin4[i] = make_float4(v.x*ph.x + v.y*ph.y, v.y*ph.x - v.x*ph.y,
                          v.z*ph.x + v.w*ph.y, v.w*ph.x - v.z*ph.y);
}

// ---------------- stage D: FFT-512 over c (zero-padded), Stockham radix-8, fused conj(phase) ----------------
#define FPAD 516   // row stride (float2) for [8][516] LDS

template<int P, bool ZTOP>
__device__ __forceinline__ void pass8x(float2* L, int fp, int i2, float sgn) {
    const int ia = i2, ib = i2 + 32;
    const int ka = ia & (P - 1), kb = ib & (P - 1);
    float2 ua[8], ub[8];
#pragma unroll
    for (int r = 0; r < 8; r++) {
        if (ZTOP && r >= 4) {
            ua[r] = make_float2(0.f, 0.f);
            ub[r] = make_float2(0.f, 0.f);
        } else {
            ua[r] = L[fp * FPAD + ia + 64 * r];
            ub[r] = L[fp * FPAD + ib + 64 * r];
        }
    }
    __syncthreads();
    if (P > 1) {
        float aba = sgn * (TWO_PI_F / (8.0f * (float)P)) * (float)ka;
        float abb = sgn * (TWO_PI_F / (8.0f * (float)P)) * (float)kb;
#pragma unroll
        for (int r = 1; r < 8; r++) {
            float sn, cs;
            __sincosf(aba * (float)r, &sn, &cs);
            ua[r] = cmul(ua[r], make_float2(cs, sn));
            __sincosf(abb * (float)r, &sn, &cs);
            ub[r] = cmul(ub[r], make_float2(cs, sn));
        }
    }
    float2 va[8], vb[8];
    dft8(ua, va, sgn);
    dft8(ub, vb, sgn);
    const int basea = 8 * P * (ia / P) + ka;
    const int baseb = 8 * P * (ib / P) + kb;
#pragma unroll
    for (int r = 0; r < 8; r++) {
        L[fp * FPAD + basea + r * P] = va[r];
        L[fp * FPAD + baseb + r * P] = vb[r];
    }
    __syncthreads();
}

__global__ __launch_bounds__(256) void fft512_kernel(const float2* __restrict__ fin,
                                                     const float2* __restrict__ ph,   // may be null
                                                     float* __restrict__ outr,
                                                     float2* __restrict__ outc,
                                                     int b0, int realOnly) {
    __shared__ float2 L[8 * FPAD];   // 33 KiB
    int wg = blockIdx.x;             // bl*512 + ftile
    int bl = wg >> 9;
    int f0 = (wg & 511) * 8;
    int t = threadIdx.x;
    int fpp = t & 7;
    int cg = t >> 3;                 // 0..31
#pragma unroll
    for (int it = 0; it < 8; it++) {
        int c = it * 32 + cg;
        float2 v = fin[((size_t)(bl * NC + c)) * NF + f0 + fpp];
        if (ph) {
            float2 p = ph[bl * NC + c];
            v = make_float2(v.x * p.x + v.y * p.y, v.y * p.x - v.x * p.y);  // f*conj(ph)
        }
        L[fpp * FPAD + c] = v;
    }
    __syncthreads();
    int fp = t & 7;
    int i2 = t >> 3;                 // 0..31
    pass8x<1, true >(L, fp, i2, -1.0f);
    pass8x<8, false>(L, fp, i2, -1.0f);
    pass8x<64, false>(L, fp, i2, -1.0f);
    size_t ob = ((size_t)((b0 + bl) * NF + f0)) * NJ;
    if (realOnly) {
#pragma unroll
        for (int fp2 = 0; fp2 < 8; fp2++)
#pragma unroll
            for (int jq = 0; jq < 2; jq++) {
                int j = t + 256 * jq;
                outr[ob + (size_t)fp2 * NJ + j] = L[fp2 * FPAD + j].x;
            }
    } else {
#pragma unroll
        for (int fp2 = 0; fp2 < 8; fp2++)
#pragma unroll
            for (int jq = 0; jq < 2; jq++) {
                int j = t + 256 * jq;
                outc[ob + (size_t)fp2 * NJ + j] = L[fp2 * FPAD + j];
            }
    }
}

// ---------------- output 0 writers (run LAST) ----------------
__global__ void copy_kernel(const float4* __restrict__ src, float4* __restrict__ dst, int n4) {
    int i = blockIdx.x * blockDim.x + threadIdx.x;
    int stride = gridDim.x * blockDim.x;
    for (; i < n4; i += stride) dst[i] = src[i];
}
__global__ void pack_x_kernel(const float2* __restrict__ xr, const float2* __restrict__ xi,
                              float4* __restrict__ out, int n4) {
    int i = blockIdx.x * blockDim.x + threadIdx.x;
    int stride = gridDim.x * blockDim.x;
    for (; i < n4; i += stride) {
        float2 r = xr[i], m = xi[i];
        out[i] = make_float4(r.x, m.x, r.y, m.y);
    }
}

extern "C" void kernel_launch(void* const* d_in, const int* in_sizes, int n_in,
                              void* d_out, int out_size, void* d_ws, size_t ws_size,
                              hipStream_t stream) {
    const float* xr = (const float*)d_in[0];
    const float* xi = (const float*)d_in[1];
    float* out = (float*)d_out;

    if (out_size < 40000000) {
        // real-only outputs: out0 = x_real (8388608 f), out3 = Re(out3) (16777216 f)
        float* out0r = out;
        float* out3r = out + 8388608;
        size_t need = (size_t)(8388608 + 524288 + 16384 + 2048) * sizeof(float2);
        if (ws_size >= need) {
            float2* fin   = (float2*)d_ws;
            float2* gpart = fin + 8388608;
            float2* gsb   = gpart + 524288;
            float2* phase = gsb + 16384;
            transpose_kernel<<<8 * 256, 256, 0, stream>>>(xr, xi, fin, 0, 7, 3);
            ifft4096_kernel<<<8 * NC, 256, 0, stream>>>(fin, 7, 3);
            gram_kernel<<<8 * 128, 256, 0, stream>>>(fin, gpart);
            gsum_kernel<<<(8 * 2048) / 256, 256, 0, stream>>>(gpart, gsb, 8 * 2048);
            scan_kernel<<<1, 64, 0, stream>>>(gsb, phase, 8);
            fft512_kernel<<<8 * 512, 256, 0, stream>>>(fin, phase, out3r, nullptr, 0, 1);
        } else {
            // two batch-half passes; fin in out0 region; gram scratch in out3 tail
            float2* fin   = (float2*)out0r;
            float2* o3f2  = (float2*)out3r;
            float2* gpart = o3f2 + (8388608 - 262144 - 8192 - 1024);
            float2* gsb   = o3f2 + (8388608 - 8192 - 1024);
            float2* phase = o3f2 + (8388608 - 1024);
            for (int p = 0; p < 2; p++) {
                int b0 = p * 4;
                transpose_kernel<<<4 * 256, 256, 0, stream>>>(xr, xi, fin, b0, 3, 2);
                ifft4096_kernel<<<4 * NC, 256, 0, stream>>>(fin, 3, 2);
                gram_kernel<<<4 * 128, 256, 0, stream>>>(fin, gpart);
                gsum_kernel<<<(4 * 2048) / 256, 256, 0, stream>>>(gpart, gsb, 4 * 2048);
                scan_kernel<<<1, 64, 0, stream>>>(gsb, phase, 4);
                scale_kernel<<<4 * 2048, 256, 0, stream>>>((float4*)fin, phase, 4 * 524288);
                fft512_kernel<<<4 * 512, 256, 0, stream>>>(fin, nullptr, out3r, nullptr, b0, 1);
            }
        }
        copy_kernel<<<2048, 256, 0, stream>>>((const float4*)xr, (float4*)out0r, 2097152);
    } else {
        // defensive path: complex outputs as float pairs
        float2* out0f2 = (float2*)out;
        float2* out3f2 = (float2*)(out + 16777216);
        float2* fin   = out0f2;
        float2* gpart = out3f2 + (16777216 - 524288 - 16384 - 2048);
        float2* gsb   = out3f2 + (16777216 - 16384 - 2048);
        float2* phase = out3f2 + (16777216 - 2048);
        transpose_kernel<<<8 * 256, 256, 0, stream>>>(xr, xi, fin, 0, 7, 3);
        ifft4096_kernel<<<8 * NC, 256, 0, stream>>>(fin, 7, 3);
        gram_kernel<<<8 * 128, 256, 0, stream>>>(fin, gpart);
        gsum_kernel<<<(8 * 2048) / 256, 256, 0, stream>>>(gpart, gsb, 8 * 2048);
        scan_kernel<<<1, 64, 0, stream>>>(gsb, phase, 8);
        scale_kernel<<<8 * 2048, 256, 0, stream>>>((float4*)fin, phase, 8 * 524288);
        fft512_kernel<<<8 * 512, 256, 0, stream>>>(fin, nullptr, nullptr, out3f2, 0, 0);
        pack_x_kernel<<<4096, 256, 0, stream>>>((const float2*)xr, (const float2*)xi,
                                                (float4*)out0f2, 4194304);
    }
}

// Round 9
// 188.422 us; speedup vs baseline: 2.3246x; 1.1156x over previous
//
#include <hip/hip_runtime.h>
#include <math.h>

#define NF 4096   // ifft length (dot axis)
#define NC 256    // scan axis length
#define NJ 512    // fft output length
#define CH 128    // gram m-chunk size
#define TWO_PI_F 6.28318530717958647692f

__device__ __forceinline__ float2 cmul(float2 a, float2 b) {
    return make_float2(a.x*b.x - a.y*b.y, a.x*b.y + a.y*b.x);
}

// ---------- register DFT primitives (verified with delta inputs) ----------
__device__ __forceinline__ void dft4i(float2& x0, float2& x1, float2& x2, float2& x3, float sgn) {
    float2 t0 = make_float2(x0.x + x2.x, x0.y + x2.y);
    float2 t1 = make_float2(x0.x - x2.x, x0.y - x2.y);
    float2 t2 = make_float2(x1.x + x3.x, x1.y + x3.y);
    float2 t3 = make_float2(x1.x - x3.x, x1.y - x3.y);
    float2 it3 = make_float2(-sgn * t3.y, sgn * t3.x);   // sgn*i*t3
    x0 = make_float2(t0.x + t2.x, t0.y + t2.y);
    x2 = make_float2(t0.x - t2.x, t0.y - t2.y);
    x1 = make_float2(t1.x + it3.x, t1.y + it3.y);
    x3 = make_float2(t1.x - it3.x, t1.y - it3.y);
}

// natural-order DFT16 in registers; v_j ends up in slot 4*(j&3) + (j>>2)
__device__ __forceinline__ void dft16(float2* u, float sgn) {
    dft4i(u[0], u[4], u[8],  u[12], sgn);
    dft4i(u[1], u[5], u[9],  u[13], sgn);
    dft4i(u[2], u[6], u[10], u[14], sgn);
    dft4i(u[3], u[7], u[11], u[15], sgn);
    const float C1 = 0.9238795325112867f, S1 = 0.3826834323650898f, R2 = 0.7071067811865476f;
    u[5]  = cmul(u[5],  make_float2(C1,  sgn * S1));
    u[6]  = cmul(u[6],  make_float2(R2,  sgn * R2));
    u[7]  = cmul(u[7],  make_float2(S1,  sgn * C1));
    u[9]  = cmul(u[9],  make_float2(R2,  sgn * R2));
    u[10] = cmul(u[10], make_float2(0.f, sgn));
    u[11] = cmul(u[11], make_float2(-R2, sgn * R2));
    u[13] = cmul(u[13], make_float2(S1,  sgn * C1));
    u[14] = cmul(u[14], make_float2(-R2, sgn * R2));
    u[15] = cmul(u[15], make_float2(-C1, -sgn * S1));
    dft4i(u[0],  u[1],  u[2],  u[3],  sgn);
    dft4i(u[4],  u[5],  u[6],  u[7],  sgn);
    dft4i(u[8],  u[9],  u[10], u[11], sgn);
    dft4i(u[12], u[13], u[14], u[15], sgn);
}

// natural-order DFT8: out v[0..7] from in u[0..7]
__device__ __forceinline__ void dft8(const float2* u, float2* v, float sgn) {
    float2 e0 = u[0], e1 = u[2], e2 = u[4], e3 = u[6];
    float2 o0 = u[1], o1 = u[3], o2 = u[5], o3 = u[7];
    dft4i(e0, e1, e2, e3, sgn);
    dft4i(o0, o1, o2, o3, sgn);
    const float R2 = 0.7071067811865476f;
    float2 w1 = make_float2(R2, sgn * R2);
    float2 w2 = make_float2(0.f, sgn);
    float2 w3 = make_float2(-R2, sgn * R2);
    float2 t1 = cmul(o1, w1), t2 = cmul(o2, w2), t3 = cmul(o3, w3);
    v[0] = make_float2(e0.x + o0.x, e0.y + o0.y);
    v[4] = make_float2(e0.x - o0.x, e0.y - o0.y);
    v[1] = make_float2(e1.x + t1.x, e1.y + t1.y);
    v[5] = make_float2(e1.x - t1.x, e1.y - t1.y);
    v[2] = make_float2(e2.x + t2.x, e2.y + t2.y);
    v[6] = make_float2(e2.x - t2.x, e2.y - t2.y);
    v[3] = make_float2(e3.x + t3.x, e3.y + t3.y);
    v[7] = make_float2(e3.x - t3.x, e3.y - t3.y);
}

// ---------------- stage A: transpose x[b,f,c] -> fin[b,c,f] (scaled), 64x64 LDS tiles ----------------
__global__ __launch_bounds__(256) void transpose_kernel(const float* __restrict__ xr,
                                                        const float* __restrict__ xi,
                                                        float2* __restrict__ fin,
                                                        int b0, int nbm1, int nbshift) {
    __shared__ float ldr[64][65];   // odd word stride -> conflict-free both phases
    __shared__ float ldi[64][65];
    int wg = blockIdx.x;
    int bl = wg & nbm1;
    int rest = wg >> nbshift;
    int ft = rest & 63;            // 64 f-tiles
    int ct = rest >> 6;            // 4 c-tiles
    int f0 = ft << 6, c0 = ct << 6;
    int t = threadIdx.x;
    int cl = t & 63;
    int rq = t >> 6;               // 0..3
    const float scale = 1.0f / (4096.0f * 1.5f);
    int bg = b0 + bl;
    const float* xrb = xr + (size_t)bg * NF * NC;
    const float* xib = xi + (size_t)bg * NF * NC;
#pragma unroll
    for (int q = 0; q < 16; q++) {
        int r = q * 4 + rq;        // f-row in tile
        size_t idx = (size_t)(f0 + r) * NC + c0 + cl;   // consecutive cl -> coalesced
        ldr[cl][r] = xrb[idx] * scale;
        ldi[cl][r] = xib[idx] * scale;
    }
    __syncthreads();
    int fl = t & 63;
#pragma unroll
    for (int q = 0; q < 16; q++) {
        int cr = q * 4 + rq;       // c-row in tile
        fin[((size_t)(bl * NC + c0 + cr)) * NF + f0 + fl] =
            make_float2(ldr[cr][fl], ldi[cr][fl]);      // consecutive fl -> coalesced
    }
}

// ---------------- stage B: IFFT-4096 in place over fin[b,c,:], Stockham radix-16 ----------------
#define IPAD(a) ((a) + ((a) >> 4))

template<int P>
__device__ __forceinline__ void pass16(float2* S, int t, float sgn) {
    const int k = t & (P - 1);
    float2 u[16];
#pragma unroll
    for (int r = 0; r < 16; r++) u[r] = S[IPAD(t + 256 * r)];
    __syncthreads();
    if (P > 1) {
        float ab = sgn * (TWO_PI_F / (16.0f * (float)P)) * (float)k;
#pragma unroll
        for (int r = 1; r < 16; r++) {
            float sn, cs; __sincosf(ab * (float)r, &sn, &cs);
            u[r] = cmul(u[r], make_float2(cs, sn));
        }
    }
    dft16(u, sgn);
    const int base = 16 * P * (t / P) + k;
#pragma unroll
    for (int j = 0; j < 16; j++) {
        const int sl = ((j & 3) << 2) | (j >> 2);
        S[IPAD(base + j * P)] = u[sl];
    }
    __syncthreads();
}

__global__ __launch_bounds__(256) void ifft4096_kernel(float2* __restrict__ fin,
                                                       int bmask, int bshift) {
    __shared__ float2 S[4352];   // 34 KiB
    int wg = blockIdx.x;
    int bl = wg & bmask;
    int c = wg >> bshift;
    int t = threadIdx.x;
    size_t base = ((size_t)(bl * NC + c)) * NF;
#pragma unroll
    for (int q = 0; q < 16; q++) {
        int f = t + 256 * q;
        S[IPAD(f)] = fin[base + f];    // coalesced 8B/lane
    }
    __syncthreads();
    pass16<1>(S, t, 1.0f);
    pass16<16>(S, t, 1.0f);
    pass16<256>(S, t, 1.0f);
#pragma unroll
    for (int q = 0; q < 16; q++) {
        int f = t + 256 * q;
        fin[base + f] = S[IPAD(f)];
    }
}

// ---------------- stage C1: banded Gram partials, k-segmented ----------------
__global__ __launch_bounds__(256) void gram_kernel(const float2* __restrict__ fin,
                                                   float2* __restrict__ gpart) {
    __shared__ float2 ring[16][CH];
    int wg = blockIdx.x;            // bl*128 + ch*4 + ks
    int bl = wg >> 7;
    int ch = (wg >> 2) & 31;
    int ks = wg & 3;
    int m0 = ch * CH;
    int k0 = ks * 64;
    int kend = k0 + 64;
    int t = threadIdx.x;
    int dgrp = t >> 5;              // 0..7 -> d = dgrp+1
    int lane = t & 31;
    for (int r = (k0 >= 8 ? k0 - 8 : 0); r <= k0; r++)
        if (t < CH) ring[r & 15][t] = fin[((size_t)(bl * NC + r)) * NF + m0 + t];
    __syncthreads();
    for (int k = k0; k < kend; k++) {
        float2 nxt;
        bool ld = (k + 1 < kend) && (t < CH);
        if (ld) nxt = fin[((size_t)(bl * NC + k + 1)) * NF + m0 + t];
        int d = dgrp + 1;
        float2 acc = make_float2(0.f, 0.f);
        if (k - d >= 0) {
            int sk = k & 15, sj = (k - d) & 15;
#pragma unroll
            for (int i = 0; i < 4; i++) {
                int m = lane + 32 * i;
                float2 a = ring[sj][m];
                float2 bb = ring[sk][m];
                acc.x += a.x * bb.x + a.y * bb.y;
                acc.y += a.x * bb.y - a.y * bb.x;
            }
        }
#pragma unroll
        for (int off = 16; off >= 1; off >>= 1) {
            acc.x += __shfl_xor(acc.x, off);
            acc.y += __shfl_xor(acc.y, off);
        }
        if (lane == 0)
            gpart[((size_t)(bl * 32 + ch) * NC + k) * 8 + dgrp] = acc;
        if (ld) ring[(k + 1) & 15][t] = nxt;
        __syncthreads();
    }
}

// ---------------- stage C2a: sum Gram partials over 32 chunks ----------------
__global__ void gsum_kernel(const float2* __restrict__ gpart, float2* __restrict__ gs, int total) {
    int e = blockIdx.x * blockDim.x + threadIdx.x;
    if (e >= total) return;
    int bl = e >> 11;
    int kd = e & 2047;
    float2 s = make_float2(0.f, 0.f);
    for (int ch = 0; ch < 32; ch++) {
        float2 v = gpart[((size_t)(bl * 32 + ch)) * 2048 + kd];
        s.x += v.x; s.y += v.y;
    }
    gs[e] = s;
}

// ---------------- stage C2b: scalar phase recurrence, sched_barrier-pinned prefetch ----------------
// One batch per lane (8 active). 4-step register groups, double-buffered; loads for the
// next group are ISSUED then pinned with sched_barrier(0) so the compiler cannot sink
// them onto the serial dependency chain. Tree-summed 8-term complex dot; rsqrtf norm.
// Blocks >0 of this dispatch do the independent out0 copy (overlapped with the scan).
#define SCAN_STEP(A0, A1, A2, A3, KIDX)  do {                                  \
    float rx0 = p1.x*A0.x - p1.y*A0.y, ry0 = p1.x*A0.y + p1.y*A0.x;            \
    float rx1 = p2.x*A0.z - p2.y*A0.w, ry1 = p2.x*A0.w + p2.y*A0.z;            \
    float rx2 = p3.x*A1.x - p3.y*A1.y, ry2 = p3.x*A1.y + p3.y*A1.x;            \
    float rx3 = p4.x*A1.z - p4.y*A1.w, ry3 = p4.x*A1.w + p4.y*A1.z;            \
    float rx4 = p5.x*A2.x - p5.y*A2.y, ry4 = p5.x*A2.y + p5.y*A2.x;            \
    float rx5 = p6.x*A2.z - p6.y*A2.w, ry5 = p6.x*A2.w + p6.y*A2.z;            \
    float rx6 = p7.x*A3.x - p7.y*A3.y, ry6 = p7.x*A3.y + p7.y*A3.x;            \
    float rx7 = p8.x*A3.z - p8.y*A3.w, ry7 = p8.x*A3.w + p8.y*A3.z;            \
    float sx = ((rx0 + rx1) + (rx2 + rx3)) + ((rx4 + rx5) + (rx6 + rx7));      \
    float sy = ((ry0 + ry1) + (ry2 + ry3)) + ((ry4 + ry5) + (ry6 + ry7));      \
    float inv = rsqrtf(sx * sx + sy * sy);                                     \
    float2 np = make_float2(sx * inv, sy * inv);                               \
    phase[t * NC + (KIDX)] = np;                                               \
    p8 = p7; p7 = p6; p6 = p5; p5 = p4; p4 = p3; p3 = p2; p2 = p1; p1 = np;    \
} while (0)

#define SCAN_LOADG4(BUF, KBASE)  do {                                          \
    _Pragma("unroll") for (int j = 0; j < 4; j++) {                            \
        _Pragma("unroll") for (int q = 0; q < 4; q++)                          \
            BUF[j][q] = gb4[((KBASE) + j) * 4 + q];                            \
    }                                                                          \
} while (0)

#define SCAN_GRP4(BUF, KBASE, FIRST)  do {                                     \
    _Pragma("unroll") for (int j = 0; j < 4; j++) {                            \
        if (FIRST && j == 0) {                                                 \
            phase[t * NC] = make_float2(1.f, 0.f);                             \
        } else {                                                               \
            SCAN_STEP(BUF[j][0], BUF[j][1], BUF[j][2], BUF[j][3], (KBASE) + j);\
        }                                                                      \
    }                                                                          \
} while (0)

__global__ __launch_bounds__(64, 1) void scan_copy_kernel(const float2* __restrict__ gs,
                                                          float2* __restrict__ phase, int nb,
                                                          const float4* __restrict__ csrc,
                                                          float4* __restrict__ cdst, int cn4) {
    if (blockIdx.x != 0) {
        int i = (blockIdx.x - 1) * 64 + threadIdx.x;
        int stride = (gridDim.x - 1) * 64;
        for (; i < cn4; i += stride) cdst[i] = csrc[i];
        return;
    }
    int t = threadIdx.x;
    if (t >= nb) return;
    const float4* gb4 = (const float4*)(gs + (size_t)t * 2048);   // 256 rows x 4 float4
    float2 z = make_float2(0.f, 0.f);
    float2 p1 = make_float2(1.f, 0.f);
    float2 p2 = z, p3 = z, p4 = z, p5 = z, p6 = z, p7 = z, p8 = z;
    float4 GA[4][4], GB[4][4];
    SCAN_LOADG4(GA, 0);
    for (int g2 = 0; g2 < 32; g2++) {
        int k0 = g2 * 8;
        SCAN_LOADG4(GB, k0 + 4);
        __builtin_amdgcn_sched_barrier(0);   // pin GB loads before GA compute
        if (g2 == 0) { SCAN_GRP4(GA, k0, true); } else { SCAN_GRP4(GA, k0, false); }
        if (g2 < 31) SCAN_LOADG4(GA, k0 + 8);
        __builtin_amdgcn_sched_barrier(0);   // pin GA-next loads before GB compute
        SCAN_GRP4(GB, k0 + 4, false);
    }
}

// ---------------- stage C3 (fallback paths only): fin *= conj(phase) ----------------
__global__ void scale_kernel(float4* __restrict__ fin4, const float2* __restrict__ phase, int n4) {
    int i = blockIdx.x * blockDim.x + threadIdx.x;
    if (i >= n4) return;
    int row = i >> 11;
    float2 ph = phase[row];
    float4 v = fin4[i];
    fin4[i] = make_float4(v.x*ph.x + v.y*ph.y, v.y*ph.x - v.x*ph.y,
                          v.z*ph.x + v.w*ph.y, v.w*ph.x - v.z*ph.y);
}

// ---------------- stage D: FFT-512 over c (zero-padded), Stockham radix-8, fused conj(phase) ----------------
#define FPAD 516   // row stride (float2) for [8][516] LDS

template<int P, bool ZTOP>
__device__ __forceinline__ void pass8x(float2* L, int fp, int i2, float sgn) {
    const int ia = i2, ib = i2 + 32;
    const int ka = ia & (P - 1), kb = ib & (P - 1);
    float2 ua[8], ub[8];
#pragma unroll
    for (int r = 0; r < 8; r++) {
        if (ZTOP && r >= 4) {
            ua[r] = make_float2(0.f, 0.f);
            ub[r] = make_float2(0.f, 0.f);
        } else {
            ua[r] = L[fp * FPAD + ia + 64 * r];
            ub[r] = L[fp * FPAD + ib + 64 * r];
        }
    }
    __syncthreads();
    if (P > 1) {
        float aba = sgn * (TWO_PI_F / (8.0f * (float)P)) * (float)ka;
        float abb = sgn * (TWO_PI_F / (8.0f * (float)P)) * (float)kb;
#pragma unroll
        for (int r = 1; r < 8; r++) {
            float sn, cs;
            __sincosf(aba * (float)r, &sn, &cs);
            ua[r] = cmul(ua[r], make_float2(cs, sn));
            __sincosf(abb * (float)r, &sn, &cs);
            ub[r] = cmul(ub[r], make_float2(cs, sn));
        }
    }
    float2 va[8], vb[8];
    dft8(ua, va, sgn);
    dft8(ub, vb, sgn);
    const int basea = 8 * P * (ia / P) + ka;
    const int baseb = 8 * P * (ib / P) + kb;
#pragma unroll
    for (int r = 0; r < 8; r++) {
        L[fp * FPAD + basea + r * P] = va[r];
        L[fp * FPAD + baseb + r * P] = vb[r];
    }
    __syncthreads();
}

__global__ __launch_bounds__(256) void fft512_kernel(const float2* __restrict__ fin,
                                                     const float2* __restrict__ ph,   // may be null
                                                     float* __restrict__ outr,
                                                     float2* __restrict__ outc,
                                                     int b0, int realOnly) {
    __shared__ float2 L[8 * FPAD];   // 33 KiB
    int wg = blockIdx.x;             // bl*512 + ftile
    int bl = wg >> 9;
    int f0 = (wg & 511) * 8;
    int t = threadIdx.x;
    int fpp = t & 7;
    int cg = t >> 3;                 // 0..31
#pragma unroll
    for (int it = 0; it < 8; it++) {
        int c = it * 32 + cg;
        float2 v = fin[((size_t)(bl * NC + c)) * NF + f0 + fpp];
        if (ph) {
            float2 p = ph[bl * NC + c];
            v = make_float2(v.x * p.x + v.y * p.y, v.y * p.x - v.x * p.y);  // f*conj(ph)
        }
        L[fpp * FPAD + c] = v;
    }
    __syncthreads();
    int fp = t & 7;
    int i2 = t >> 3;                 // 0..31
    pass8x<1, true >(L, fp, i2, -1.0f);
    pass8x<8, false>(L, fp, i2, -1.0f);
    pass8x<64, false>(L, fp, i2, -1.0f);
    size_t ob = ((size_t)((b0 + bl) * NF + f0)) * NJ;
    if (realOnly) {
#pragma unroll
        for (int fp2 = 0; fp2 < 8; fp2++)
#pragma unroll
            for (int jq = 0; jq < 2; jq++) {
                int j = t + 256 * jq;
                outr[ob + (size_t)fp2 * NJ + j] = L[fp2 * FPAD + j].x;
            }
    } else {
#pragma unroll
        for (int fp2 = 0; fp2 < 8; fp2++)
#pragma unroll
            for (int jq = 0; jq < 2; jq++) {
                int j = t + 256 * jq;
                outc[ob + (size_t)fp2 * NJ + j] = L[fp2 * FPAD + j];
            }
    }
}

// ---------------- output 0 writers (fallback paths) ----------------
__global__ void copy_kernel(const float4* __restrict__ src, float4* __restrict__ dst, int n4) {
    int i = blockIdx.x * blockDim.x + threadIdx.x;
    int stride = gridDim.x * blockDim.x;
    for (; i < n4; i += stride) dst[i] = src[i];
}
__global__ void pack_x_kernel(const float2* __restrict__ xr, const float2* __restrict__ xi,
                              float4* __restrict__ out, int n4) {
    int i = blockIdx.x * blockDim.x + threadIdx.x;
    int stride = gridDim.x * blockDim.x;
    for (; i < n4; i += stride) {
        float2 r = xr[i], m = xi[i];
        out[i] = make_float4(r.x, m.x, r.y, m.y);
    }
}

extern "C" void kernel_launch(void* const* d_in, const int* in_sizes, int n_in,
                              void* d_out, int out_size, void* d_ws, size_t ws_size,
                              hipStream_t stream) {
    const float* xr = (const float*)d_in[0];
    const float* xi = (const float*)d_in[1];
    float* out = (float*)d_out;

    if (out_size < 40000000) {
        // real-only outputs: out0 = x_real (8388608 f), out3 = Re(out3) (16777216 f)
        float* out0r = out;
        float* out3r = out + 8388608;
        size_t need = (size_t)(8388608 + 524288 + 16384 + 2048) * sizeof(float2);
        if (ws_size >= need) {
            float2* fin   = (float2*)d_ws;
            float2* gpart = fin + 8388608;
            float2* gsb   = gpart + 524288;
            float2* phase = gsb + 16384;
            transpose_kernel<<<8 * 256, 256, 0, stream>>>(xr, xi, fin, 0, 7, 3);
            ifft4096_kernel<<<8 * NC, 256, 0, stream>>>(fin, 7, 3);
            gram_kernel<<<8 * 128, 256, 0, stream>>>(fin, gpart);
            gsum_kernel<<<(8 * 2048) / 256, 256, 0, stream>>>(gpart, gsb, 8 * 2048);
            // block 0: serial scan; blocks 1..2048: out0 copy (independent, overlapped)
            scan_copy_kernel<<<2049, 64, 0, stream>>>(gsb, phase, 8,
                                                      (const float4*)xr, (float4*)out0r, 2097152);
            fft512_kernel<<<8 * 512, 256, 0, stream>>>(fin, phase, out3r, nullptr, 0, 1);
        } else {
            // two batch-half passes; fin in out0 region; gram scratch in out3 tail
            float2* fin   = (float2*)out0r;
            float2* o3f2  = (float2*)out3r;
            float2* gpart = o3f2 + (8388608 - 262144 - 8192 - 1024);
            float2* gsb   = o3f2 + (8388608 - 8192 - 1024);
            float2* phase = o3f2 + (8388608 - 1024);
            for (int p = 0; p < 2; p++) {
                int b0 = p * 4;
                transpose_kernel<<<4 * 256, 256, 0, stream>>>(xr, xi, fin, b0, 3, 2);
                ifft4096_kernel<<<4 * NC, 256, 0, stream>>>(fin, 3, 2);
                gram_kernel<<<4 * 128, 256, 0, stream>>>(fin, gpart);
                gsum_kernel<<<(4 * 2048) / 256, 256, 0, stream>>>(gpart, gsb, 4 * 2048);
                scan_copy_kernel<<<1, 64, 0, stream>>>(gsb, phase, 4, nullptr, nullptr, 0);
                scale_kernel<<<4 * 2048, 256, 0, stream>>>((float4*)fin, phase, 4 * 524288);
                fft512_kernel<<<4 * 512, 256, 0, stream>>>(fin, nullptr, out3r, nullptr, b0, 1);
            }
            copy_kernel<<<2048, 256, 0, stream>>>((const float4*)xr, (float4*)out0r, 2097152);
        }
    } else {
        // defensive path: complex outputs as float pairs
        float2* out0f2 = (float2*)out;
        float2* out3f2 = (float2*)(out + 16777216);
        float2* fin   = out0f2;
        float2* gpart = out3f2 + (16777216 - 524288 - 16384 - 2048);
        float2* gsb   = out3f2 + (16777216 - 16384 - 2048);
        float2* phase = out3f2 + (16777216 - 2048);
        transpose_kernel<<<8 * 256, 256, 0, stream>>>(xr, xi, fin, 0, 7, 3);
        ifft4096_kernel<<<8 * NC, 256, 0, stream>>>(fin, 7, 3);
        gram_kernel<<<8 * 128, 256, 0, stream>>>(fin, gpart);
        gsum_kernel<<<(8 * 2048) / 256, 256, 0, stream>>>(gpart, gsb, 8 * 2048);
        scan_copy_kernel<<<1, 64, 0, stream>>>(gsb, phase, 8, nullptr, nullptr, 0);
        scale_kernel<<<8 * 2048, 256, 0, stream>>>((float4*)fin, phase, 8 * 524288);
        fft512_kernel<<<8 * 512, 256, 0, stream>>>(fin, nullptr, nullptr, out3f2, 0, 0);
        pack_x_kernel<<<4096, 256, 0, stream>>>((const float2*)xr, (const float2*)xi,
                                                (float4*)out0f2, 4194304);
    }
}

// Round 10
// 186.747 us; speedup vs baseline: 2.3455x; 1.0090x over previous
//
#include <hip/hip_runtime.h>
#include <math.h>

#define NF 4096   // ifft length (dot axis)
#define NC 256    // scan axis length
#define NJ 512    // fft output length
#define CH 128    // gram m-chunk size
#define TWO_PI_F 6.28318530717958647692f

__device__ __forceinline__ float2 cmul(float2 a, float2 b) {
    return make_float2(a.x*b.x - a.y*b.y, a.x*b.y + a.y*b.x);
}

// ---------- register DFT primitives (verified with delta inputs) ----------
__device__ __forceinline__ void dft4i(float2& x0, float2& x1, float2& x2, float2& x3, float sgn) {
    float2 t0 = make_float2(x0.x + x2.x, x0.y + x2.y);
    float2 t1 = make_float2(x0.x - x2.x, x0.y - x2.y);
    float2 t2 = make_float2(x1.x + x3.x, x1.y + x3.y);
    float2 t3 = make_float2(x1.x - x3.x, x1.y - x3.y);
    float2 it3 = make_float2(-sgn * t3.y, sgn * t3.x);   // sgn*i*t3
    x0 = make_float2(t0.x + t2.x, t0.y + t2.y);
    x2 = make_float2(t0.x - t2.x, t0.y - t2.y);
    x1 = make_float2(t1.x + it3.x, t1.y + it3.y);
    x3 = make_float2(t1.x - it3.x, t1.y - it3.y);
}

// natural-order DFT16 in registers; v_j ends up in slot 4*(j&3) + (j>>2)
__device__ __forceinline__ void dft16(float2* u, float sgn) {
    dft4i(u[0], u[4], u[8],  u[12], sgn);
    dft4i(u[1], u[5], u[9],  u[13], sgn);
    dft4i(u[2], u[6], u[10], u[14], sgn);
    dft4i(u[3], u[7], u[11], u[15], sgn);
    const float C1 = 0.9238795325112867f, S1 = 0.3826834323650898f, R2 = 0.7071067811865476f;
    u[5]  = cmul(u[5],  make_float2(C1,  sgn * S1));
    u[6]  = cmul(u[6],  make_float2(R2,  sgn * R2));
    u[7]  = cmul(u[7],  make_float2(S1,  sgn * C1));
    u[9]  = cmul(u[9],  make_float2(R2,  sgn * R2));
    u[10] = cmul(u[10], make_float2(0.f, sgn));
    u[11] = cmul(u[11], make_float2(-R2, sgn * R2));
    u[13] = cmul(u[13], make_float2(S1,  sgn * C1));
    u[14] = cmul(u[14], make_float2(-R2, sgn * R2));
    u[15] = cmul(u[15], make_float2(-C1, -sgn * S1));
    dft4i(u[0],  u[1],  u[2],  u[3],  sgn);
    dft4i(u[4],  u[5],  u[6],  u[7],  sgn);
    dft4i(u[8],  u[9],  u[10], u[11], sgn);
    dft4i(u[12], u[13], u[14], u[15], sgn);
}

// natural-order DFT8: out v[0..7] from in u[0..7]
__device__ __forceinline__ void dft8(const float2* u, float2* v, float sgn) {
    float2 e0 = u[0], e1 = u[2], e2 = u[4], e3 = u[6];
    float2 o0 = u[1], o1 = u[3], o2 = u[5], o3 = u[7];
    dft4i(e0, e1, e2, e3, sgn);
    dft4i(o0, o1, o2, o3, sgn);
    const float R2 = 0.7071067811865476f;
    float2 w1 = make_float2(R2, sgn * R2);
    float2 w2 = make_float2(0.f, sgn);
    float2 w3 = make_float2(-R2, sgn * R2);
    float2 t1 = cmul(o1, w1), t2 = cmul(o2, w2), t3 = cmul(o3, w3);
    v[0] = make_float2(e0.x + o0.x, e0.y + o0.y);
    v[4] = make_float2(e0.x - o0.x, e0.y - o0.y);
    v[1] = make_float2(e1.x + t1.x, e1.y + t1.y);
    v[5] = make_float2(e1.x - t1.x, e1.y - t1.y);
    v[2] = make_float2(e2.x + t2.x, e2.y + t2.y);
    v[6] = make_float2(e2.x - t2.x, e2.y - t2.y);
    v[3] = make_float2(e3.x + t3.x, e3.y + t3.y);
    v[7] = make_float2(e3.x - t3.x, e3.y - t3.y);
}

// ---------------- stage A: transpose x[b,f,c] -> fin[b,c,f] (scaled), 64x64 LDS tiles ----------------
__global__ __launch_bounds__(256) void transpose_kernel(const float* __restrict__ xr,
                                                        const float* __restrict__ xi,
                                                        float2* __restrict__ fin,
                                                        int b0, int nbm1, int nbshift) {
    __shared__ float ldr[64][65];   // odd word stride -> conflict-free both phases
    __shared__ float ldi[64][65];
    int wg = blockIdx.x;
    int bl = wg & nbm1;
    int rest = wg >> nbshift;
    int ft = rest & 63;            // 64 f-tiles
    int ct = rest >> 6;            // 4 c-tiles
    int f0 = ft << 6, c0 = ct << 6;
    int t = threadIdx.x;
    int cl = t & 63;
    int rq = t >> 6;               // 0..3
    const float scale = 1.0f / (4096.0f * 1.5f);
    int bg = b0 + bl;
    const float* xrb = xr + (size_t)bg * NF * NC;
    const float* xib = xi + (size_t)bg * NF * NC;
#pragma unroll
    for (int q = 0; q < 16; q++) {
        int r = q * 4 + rq;        // f-row in tile
        size_t idx = (size_t)(f0 + r) * NC + c0 + cl;   // consecutive cl -> coalesced
        ldr[cl][r] = xrb[idx] * scale;
        ldi[cl][r] = xib[idx] * scale;
    }
    __syncthreads();
    int fl = t & 63;
#pragma unroll
    for (int q = 0; q < 16; q++) {
        int cr = q * 4 + rq;       // c-row in tile
        fin[((size_t)(bl * NC + c0 + cr)) * NF + f0 + fl] =
            make_float2(ldr[cr][fl], ldi[cr][fl]);      // consecutive fl -> coalesced
    }
}

// ---------------- stage B: IFFT-4096 in place over fin[b,c,:], Stockham radix-16 ----------------
#define IPAD(a) ((a) + ((a) >> 4))

template<int P>
__device__ __forceinline__ void pass16(float2* S, int t, float sgn) {
    const int k = t & (P - 1);
    float2 u[16];
#pragma unroll
    for (int r = 0; r < 16; r++) u[r] = S[IPAD(t + 256 * r)];
    __syncthreads();
    if (P > 1) {
        float ab = sgn * (TWO_PI_F / (16.0f * (float)P)) * (float)k;
#pragma unroll
        for (int r = 1; r < 16; r++) {
            float sn, cs; __sincosf(ab * (float)r, &sn, &cs);
            u[r] = cmul(u[r], make_float2(cs, sn));
        }
    }
    dft16(u, sgn);
    const int base = 16 * P * (t / P) + k;
#pragma unroll
    for (int j = 0; j < 16; j++) {
        const int sl = ((j & 3) << 2) | (j >> 2);
        S[IPAD(base + j * P)] = u[sl];
    }
    __syncthreads();
}

__global__ __launch_bounds__(256) void ifft4096_kernel(float2* __restrict__ fin,
                                                       int bmask, int bshift) {
    __shared__ float2 S[4352];   // 34 KiB
    int wg = blockIdx.x;
    int bl = wg & bmask;
    int c = wg >> bshift;
    int t = threadIdx.x;
    size_t base = ((size_t)(bl * NC + c)) * NF;
#pragma unroll
    for (int q = 0; q < 16; q++) {
        int f = t + 256 * q;
        S[IPAD(f)] = fin[base + f];    // coalesced 8B/lane
    }
    __syncthreads();
    pass16<1>(S, t, 1.0f);
    pass16<16>(S, t, 1.0f);
    pass16<256>(S, t, 1.0f);
#pragma unroll
    for (int q = 0; q < 16; q++) {
        int f = t + 256 * q;
        fin[base + f] = S[IPAD(f)];
    }
}

// ---------------- stage C1: banded Gram partials, k-tiled bulk-LDS ----------------
// WG = (bl, ks: 32-k tile, ch: 128-m chunk). Bulk-load 40 rows (32 + 8 halo) into
// planar re/im LDS (row stride 129 -> bank=(row+lane)%32, 2 lanes/bank = free), one
// barrier, then all 32x8 dots from LDS with shuffle reduce. No per-k barrier/load.
#define GSTR 129
__global__ __launch_bounds__(256) void gram_kernel(const float2* __restrict__ fin,
                                                   float2* __restrict__ gpart) {
    __shared__ float lre[40 * GSTR];   // 20.6 KiB
    __shared__ float lim[40 * GSTR];   // 20.6 KiB
    int wg = blockIdx.x;            // ((bl*8)+ks)*32 + ch
    int bl = wg >> 8;
    int ks = (wg >> 5) & 7;
    int ch = wg & 31;
    int m0 = ch * CH;
    int k0 = ks * 32;
    int t = threadIdx.x;
    // bulk load: 40 rows x 128 float2, coalesced (2 rows per 256-thread iteration)
#pragma unroll
    for (int q = 0; q < 20; q++) {
        int e = t + 256 * q;
        int row = e >> 7;
        int m = e & 127;
        int gk = k0 - 8 + row;
        float2 v = (gk >= 0) ? fin[((size_t)(bl * NC + gk)) * NF + m0 + m]
                             : make_float2(0.f, 0.f);
        lre[row * GSTR + m] = v.x;
        lim[row * GSTR + m] = v.y;
    }
    __syncthreads();
    int dgrp = t >> 5;              // 0..7 -> d = dgrp+1
    int lane = t & 31;
    int d = dgrp + 1;
#pragma unroll
    for (int kk = 0; kk < 32; kk++) {
        int k = k0 + kk;
        float2 acc = make_float2(0.f, 0.f);
        if (k - d >= 0) {
            const float* ar = &lre[(kk + 8 - d) * GSTR];
            const float* ai = &lim[(kk + 8 - d) * GSTR];
            const float* br = &lre[(kk + 8) * GSTR];
            const float* bi = &lim[(kk + 8) * GSTR];
#pragma unroll
            for (int i = 0; i < 4; i++) {
                int m = lane + 32 * i;
                float ax = ar[m], ay = ai[m];
                float bx = br[m], by = bi[m];
                acc.x += ax * bx + ay * by;   // conj(a)*b
                acc.y += ax * by - ay * bx;
            }
        }
#pragma unroll
        for (int off = 16; off >= 1; off >>= 1) {
            acc.x += __shfl_xor(acc.x, off);
            acc.y += __shfl_xor(acc.y, off);
        }
        if (lane == 0)   // d>k rows stay exact zeros -> no poison downstream
            gpart[((size_t)(bl * 32 + ch) * NC + k) * 8 + dgrp] = acc;
    }
}

// ---------------- stage C2a: sum Gram partials over 32 chunks ----------------
__global__ void gsum_kernel(const float2* __restrict__ gpart, float2* __restrict__ gs, int total) {
    int e = blockIdx.x * blockDim.x + threadIdx.x;
    if (e >= total) return;
    int bl = e >> 11;
    int kd = e & 2047;
    float2 s = make_float2(0.f, 0.f);
    for (int ch = 0; ch < 32; ch++) {
        float2 v = gpart[((size_t)(bl * 32 + ch)) * 2048 + kd];
        s.x += v.x; s.y += v.y;
    }
    gs[e] = s;
}

// ---------------- stage C2b: scalar phase recurrence, sched_barrier-pinned prefetch ----------------
#define SCAN_STEP(A0, A1, A2, A3, KIDX)  do {                                  \
    float rx0 = p1.x*A0.x - p1.y*A0.y, ry0 = p1.x*A0.y + p1.y*A0.x;            \
    float rx1 = p2.x*A0.z - p2.y*A0.w, ry1 = p2.x*A0.w + p2.y*A0.z;            \
    float rx2 = p3.x*A1.x - p3.y*A1.y, ry2 = p3.x*A1.y + p3.y*A1.x;            \
    float rx3 = p4.x*A1.z - p4.y*A1.w, ry3 = p4.x*A1.w + p4.y*A1.z;            \
    float rx4 = p5.x*A2.x - p5.y*A2.y, ry4 = p5.x*A2.y + p5.y*A2.x;            \
    float rx5 = p6.x*A2.z - p6.y*A2.w, ry5 = p6.x*A2.w + p6.y*A2.z;            \
    float rx6 = p7.x*A3.x - p7.y*A3.y, ry6 = p7.x*A3.y + p7.y*A3.x;            \
    float rx7 = p8.x*A3.z - p8.y*A3.w, ry7 = p8.x*A3.w + p8.y*A3.z;            \
    float sx = ((rx0 + rx1) + (rx2 + rx3)) + ((rx4 + rx5) + (rx6 + rx7));      \
    float sy = ((ry0 + ry1) + (ry2 + ry3)) + ((ry4 + ry5) + (ry6 + ry7));      \
    float inv = rsqrtf(sx * sx + sy * sy);                                     \
    float2 np = make_float2(sx * inv, sy * inv);                               \
    phase[t * NC + (KIDX)] = np;                                               \
    p8 = p7; p7 = p6; p6 = p5; p5 = p4; p4 = p3; p3 = p2; p2 = p1; p1 = np;    \
} while (0)

#define SCAN_LOADG4(BUF, KBASE)  do {                                          \
    _Pragma("unroll") for (int j = 0; j < 4; j++) {                            \
        _Pragma("unroll") for (int q = 0; q < 4; q++)                          \
            BUF[j][q] = gb4[((KBASE) + j) * 4 + q];                            \
    }                                                                          \
} while (0)

#define SCAN_GRP4(BUF, KBASE, FIRST)  do {                                     \
    _Pragma("unroll") for (int j = 0; j < 4; j++) {                            \
        if (FIRST && j == 0) {                                                 \
            phase[t * NC] = make_float2(1.f, 0.f);                             \
        } else {                                                               \
            SCAN_STEP(BUF[j][0], BUF[j][1], BUF[j][2], BUF[j][3], (KBASE) + j);\
        }                                                                      \
    }                                                                          \
} while (0)

__global__ __launch_bounds__(64, 1) void scan_copy_kernel(const float2* __restrict__ gs,
                                                          float2* __restrict__ phase, int nb,
                                                          const float4* __restrict__ csrc,
                                                          float4* __restrict__ cdst, int cn4) {
    if (blockIdx.x != 0) {
        int i = (blockIdx.x - 1) * 64 + threadIdx.x;
        int stride = (gridDim.x - 1) * 64;
        for (; i < cn4; i += stride) cdst[i] = csrc[i];
        return;
    }
    int t = threadIdx.x;
    if (t >= nb) return;
    const float4* gb4 = (const float4*)(gs + (size_t)t * 2048);   // 256 rows x 4 float4
    float2 z = make_float2(0.f, 0.f);
    float2 p1 = make_float2(1.f, 0.f);
    float2 p2 = z, p3 = z, p4 = z, p5 = z, p6 = z, p7 = z, p8 = z;
    float4 GA[4][4], GB[4][4];
    SCAN_LOADG4(GA, 0);
    for (int g2 = 0; g2 < 32; g2++) {
        int k0 = g2 * 8;
        SCAN_LOADG4(GB, k0 + 4);
        __builtin_amdgcn_sched_barrier(0);   // pin GB loads before GA compute
        if (g2 == 0) { SCAN_GRP4(GA, k0, true); } else { SCAN_GRP4(GA, k0, false); }
        if (g2 < 31) SCAN_LOADG4(GA, k0 + 8);
        __builtin_amdgcn_sched_barrier(0);   // pin GA-next loads before GB compute
        SCAN_GRP4(GB, k0 + 4, false);
    }
}

// ---------------- stage C3 (fallback paths only): fin *= conj(phase) ----------------
__global__ void scale_kernel(float4* __restrict__ fin4, const float2* __restrict__ phase, int n4) {
    int i = blockIdx.x * blockDim.x + threadIdx.x;
    if (i >= n4) return;
    int row = i >> 11;
    float2 ph = phase[row];
    float4 v = fin4[i];
    fin4[i] = make_float4(v.x*ph.x + v.y*ph.y, v.y*ph.x - v.x*ph.y,
                          v.z*ph.x + v.w*ph.y, v.w*ph.x - v.z*ph.y);
}

// ---------------- stage D: FFT-512 over c (zero-padded), Stockham radix-8, fused conj(phase) ----------------
#define FPAD 516   // row stride (float2) for [8][516] LDS

template<int P, bool ZTOP>
__device__ __forceinline__ void pass8x(float2* L, int fp, int i2, float sgn) {
    const int ia = i2, ib = i2 + 32;
    const int ka = ia & (P - 1), kb = ib & (P - 1);
    float2 ua[8], ub[8];
#pragma unroll
    for (int r = 0; r < 8; r++) {
        if (ZTOP && r >= 4) {
            ua[r] = make_float2(0.f, 0.f);
            ub[r] = make_float2(0.f, 0.f);
        } else {
            ua[r] = L[fp * FPAD + ia + 64 * r];
            ub[r] = L[fp * FPAD + ib + 64 * r];
        }
    }
    __syncthreads();
    if (P > 1) {
        float aba = sgn * (TWO_PI_F / (8.0f * (float)P)) * (float)ka;
        float abb = sgn * (TWO_PI_F / (8.0f * (float)P)) * (float)kb;
#pragma unroll
        for (int r = 1; r < 8; r++) {
            float sn, cs;
            __sincosf(aba * (float)r, &sn, &cs);
            ua[r] = cmul(ua[r], make_float2(cs, sn));
            __sincosf(abb * (float)r, &sn, &cs);
            ub[r] = cmul(ub[r], make_float2(cs, sn));
        }
    }
    float2 va[8], vb[8];
    dft8(ua, va, sgn);
    dft8(ub, vb, sgn);
    const int basea = 8 * P * (ia / P) + ka;
    const int baseb = 8 * P * (ib / P) + kb;
#pragma unroll
    for (int r = 0; r < 8; r++) {
        L[fp * FPAD + basea + r * P] = va[r];
        L[fp * FPAD + baseb + r * P] = vb[r];
    }
    __syncthreads();
}

__global__ __launch_bounds__(256) void fft512_kernel(const float2* __restrict__ fin,
                                                     const float2* __restrict__ ph,   // may be null
                                                     float* __restrict__ outr,
                                                     float2* __restrict__ outc,
                                                     int b0, int realOnly) {
    __shared__ float2 L[8 * FPAD];   // 33 KiB
    int wg = blockIdx.x;             // bl*512 + ftile
    int bl = wg >> 9;
    int f0 = (wg & 511) * 8;
    int t = threadIdx.x;
    int fpp = t & 7;
    int cg = t >> 3;                 // 0..31
#pragma unroll
    for (int it = 0; it < 8; it++) {
        int c = it * 32 + cg;
        float2 v = fin[((size_t)(bl * NC + c)) * NF + f0 + fpp];
        if (ph) {
            float2 p = ph[bl * NC + c];
            v = make_float2(v.x * p.x + v.y * p.y, v.y * p.x - v.x * p.y);  // f*conj(ph)
        }
        L[fpp * FPAD + c] = v;
    }
    __syncthreads();
    int fp = t & 7;
    int i2 = t >> 3;                 // 0..31
    pass8x<1, true >(L, fp, i2, -1.0f);
    pass8x<8, false>(L, fp, i2, -1.0f);
    pass8x<64, false>(L, fp, i2, -1.0f);
    size_t ob = ((size_t)((b0 + bl) * NF + f0)) * NJ;
    if (realOnly) {
#pragma unroll
        for (int fp2 = 0; fp2 < 8; fp2++)
#pragma unroll
            for (int jq = 0; jq < 2; jq++) {
                int j = t + 256 * jq;
                outr[ob + (size_t)fp2 * NJ + j] = L[fp2 * FPAD + j].x;
            }
    } else {
#pragma unroll
        for (int fp2 = 0; fp2 < 8; fp2++)
#pragma unroll
            for (int jq = 0; jq < 2; jq++) {
                int j = t + 256 * jq;
                outc[ob + (size_t)fp2 * NJ + j] = L[fp2 * FPAD + j];
            }
    }
}

// ---------------- output 0 writers (fallback paths) ----------------
__global__ void copy_kernel(const float4* __restrict__ src, float4* __restrict__ dst, int n4) {
    int i = blockIdx.x * blockDim.x + threadIdx.x;
    int stride = gridDim.x * blockDim.x;
    for (; i < n4; i += stride) dst[i] = src[i];
}
__global__ void pack_x_kernel(const float2* __restrict__ xr, const float2* __restrict__ xi,
                              float4* __restrict__ out, int n4) {
    int i = blockIdx.x * blockDim.x + threadIdx.x;
    int stride = gridDim.x * blockDim.x;
    for (; i < n4; i += stride) {
        float2 r = xr[i], m = xi[i];
        out[i] = make_float4(r.x, m.x, r.y, m.y);
    }
}

extern "C" void kernel_launch(void* const* d_in, const int* in_sizes, int n_in,
                              void* d_out, int out_size, void* d_ws, size_t ws_size,
                              hipStream_t stream) {
    const float* xr = (const float*)d_in[0];
    const float* xi = (const float*)d_in[1];
    float* out = (float*)d_out;

    if (out_size < 40000000) {
        // real-only outputs: out0 = x_real (8388608 f), out3 = Re(out3) (16777216 f)
        float* out0r = out;
        float* out3r = out + 8388608;
        size_t need = (size_t)(8388608 + 524288 + 16384 + 2048) * sizeof(float2);
        if (ws_size >= need) {
            float2* fin   = (float2*)d_ws;
            float2* gpart = fin + 8388608;
            float2* gsb   = gpart + 524288;
            float2* phase = gsb + 16384;
            transpose_kernel<<<8 * 256, 256, 0, stream>>>(xr, xi, fin, 0, 7, 3);
            ifft4096_kernel<<<8 * NC, 256, 0, stream>>>(fin, 7, 3);
            gram_kernel<<<8 * 256, 256, 0, stream>>>(fin, gpart);
            gsum_kernel<<<(8 * 2048) / 256, 256, 0, stream>>>(gpart, gsb, 8 * 2048);
            // block 0: serial scan; blocks 1..2048: out0 copy (independent, overlapped)
            scan_copy_kernel<<<2049, 64, 0, stream>>>(gsb, phase, 8,
                                                      (const float4*)xr, (float4*)out0r, 2097152);
            fft512_kernel<<<8 * 512, 256, 0, stream>>>(fin, phase, out3r, nullptr, 0, 1);
        } else {
            // two batch-half passes; fin in out0 region; gram scratch in out3 tail
            float2* fin   = (float2*)out0r;
            float2* o3f2  = (float2*)out3r;
            float2* gpart = o3f2 + (8388608 - 262144 - 8192 - 1024);
            float2* gsb   = o3f2 + (8388608 - 8192 - 1024);
            float2* phase = o3f2 + (8388608 - 1024);
            for (int p = 0; p < 2; p++) {
                int b0 = p * 4;
                transpose_kernel<<<4 * 256, 256, 0, stream>>>(xr, xi, fin, b0, 3, 2);
                ifft4096_kernel<<<4 * NC, 256, 0, stream>>>(fin, 3, 2);
                gram_kernel<<<4 * 256, 256, 0, stream>>>(fin, gpart);
                gsum_kernel<<<(4 * 2048) / 256, 256, 0, stream>>>(gpart, gsb, 4 * 2048);
                scan_copy_kernel<<<1, 64, 0, stream>>>(gsb, phase, 4, nullptr, nullptr, 0);
                scale_kernel<<<4 * 2048, 256, 0, stream>>>((float4*)fin, phase, 4 * 524288);
                fft512_kernel<<<4 * 512, 256, 0, stream>>>(fin, nullptr, out3r, nullptr, b0, 1);
            }
            copy_kernel<<<2048, 256, 0, stream>>>((const float4*)xr, (float4*)out0r, 2097152);
        }
    } else {
        // defensive path: complex outputs as float pairs
        float2* out0f2 = (float2*)out;
        float2* out3f2 = (float2*)(out + 16777216);
        float2* fin   = out0f2;
        float2* gpart = out3f2 + (16777216 - 524288 - 16384 - 2048);
        float2* gsb   = out3f2 + (16777216 - 16384 - 2048);
        float2* phase = out3f2 + (16777216 - 2048);
        transpose_kernel<<<8 * 256, 256, 0, stream>>>(xr, xi, fin, 0, 7, 3);
        ifft4096_kernel<<<8 * NC, 256, 0, stream>>>(fin, 7, 3);
        gram_kernel<<<8 * 256, 256, 0, stream>>>(fin, gpart);
        gsum_kernel<<<(8 * 2048) / 256, 256, 0, stream>>>(gpart, gsb, 8 * 2048);
        scan_copy_kernel<<<1, 64, 0, stream>>>(gsb, phase, 8, nullptr, nullptr, 0);
        scale_kernel<<<8 * 2048, 256, 0, stream>>>((float4*)fin, phase, 8 * 524288);
        fft512_kernel<<<8 * 512, 256, 0, stream>>>(fin, nullptr, nullptr, out3f2, 0, 0);
        pack_x_kernel<<<4096, 256, 0, stream>>>((const float2*)xr, (const float2*)xi,
                                                (float4*)out0f2, 4194304);
    }
}

// Round 12
// 180.820 us; speedup vs baseline: 2.4223x; 1.0328x over previous
//
#include <hip/hip_runtime.h>
#include <math.h>

#define NF 4096   // ifft length (dot axis)
#define NC 256    // scan axis length
#define NJ 512    // fft output length
#define CH 128    // gram m-chunk size
#define TWO_PI_F 6.28318530717958647692f

__device__ __forceinline__ float2 cmul(float2 a, float2 b) {
    return make_float2(a.x*b.x - a.y*b.y, a.x*b.y + a.y*b.x);
}

// ---------- register DFT primitives (verified with delta inputs) ----------
__device__ __forceinline__ void dft4i(float2& x0, float2& x1, float2& x2, float2& x3, float sgn) {
    float2 t0 = make_float2(x0.x + x2.x, x0.y + x2.y);
    float2 t1 = make_float2(x0.x - x2.x, x0.y - x2.y);
    float2 t2 = make_float2(x1.x + x3.x, x1.y + x3.y);
    float2 t3 = make_float2(x1.x - x3.x, x1.y - x3.y);
    float2 it3 = make_float2(-sgn * t3.y, sgn * t3.x);   // sgn*i*t3
    x0 = make_float2(t0.x + t2.x, t0.y + t2.y);
    x2 = make_float2(t0.x - t2.x, t0.y - t2.y);
    x1 = make_float2(t1.x + it3.x, t1.y + it3.y);
    x3 = make_float2(t1.x - it3.x, t1.y - it3.y);
}

// natural-order DFT16 in registers; v_j ends up in slot 4*(j&3) + (j>>2)
__device__ __forceinline__ void dft16(float2* u, float sgn) {
    dft4i(u[0], u[4], u[8],  u[12], sgn);
    dft4i(u[1], u[5], u[9],  u[13], sgn);
    dft4i(u[2], u[6], u[10], u[14], sgn);
    dft4i(u[3], u[7], u[11], u[15], sgn);
    const float C1 = 0.9238795325112867f, S1 = 0.3826834323650898f, R2 = 0.7071067811865476f;
    u[5]  = cmul(u[5],  make_float2(C1,  sgn * S1));
    u[6]  = cmul(u[6],  make_float2(R2,  sgn * R2));
    u[7]  = cmul(u[7],  make_float2(S1,  sgn * C1));
    u[9]  = cmul(u[9],  make_float2(R2,  sgn * R2));
    u[10] = cmul(u[10], make_float2(0.f, sgn));
    u[11] = cmul(u[11], make_float2(-R2, sgn * R2));
    u[13] = cmul(u[13], make_float2(S1,  sgn * C1));
    u[14] = cmul(u[14], make_float2(-R2, sgn * R2));
    u[15] = cmul(u[15], make_float2(-C1, -sgn * S1));
    dft4i(u[0],  u[1],  u[2],  u[3],  sgn);
    dft4i(u[4],  u[5],  u[6],  u[7],  sgn);
    dft4i(u[8],  u[9],  u[10], u[11], sgn);
    dft4i(u[12], u[13], u[14], u[15], sgn);
}

// natural-order DFT8: out v[0..7] from in u[0..7]
__device__ __forceinline__ void dft8(const float2* u, float2* v, float sgn) {
    float2 e0 = u[0], e1 = u[2], e2 = u[4], e3 = u[6];
    float2 o0 = u[1], o1 = u[3], o2 = u[5], o3 = u[7];
    dft4i(e0, e1, e2, e3, sgn);
    dft4i(o0, o1, o2, o3, sgn);
    const float R2 = 0.7071067811865476f;
    float2 w1 = make_float2(R2, sgn * R2);
    float2 w2 = make_float2(0.f, sgn);
    float2 w3 = make_float2(-R2, sgn * R2);
    float2 t1 = cmul(o1, w1), t2 = cmul(o2, w2), t3 = cmul(o3, w3);
    v[0] = make_float2(e0.x + o0.x, e0.y + o0.y);
    v[4] = make_float2(e0.x - o0.x, e0.y - o0.y);
    v[1] = make_float2(e1.x + t1.x, e1.y + t1.y);
    v[5] = make_float2(e1.x - t1.x, e1.y - t1.y);
    v[2] = make_float2(e2.x + t2.x, e2.y + t2.y);
    v[6] = make_float2(e2.x - t2.x, e2.y - t2.y);
    v[3] = make_float2(e3.x + t3.x, e3.y + t3.y);
    v[7] = make_float2(e3.x - t3.x, e3.y - t3.y);
}

// ---------------- stage A: transpose x[b,f,c] -> fin[b,c,f] (scaled), 64x64 LDS tiles ----------------
__global__ __launch_bounds__(256) void transpose_kernel(const float* __restrict__ xr,
                                                        const float* __restrict__ xi,
                                                        float2* __restrict__ fin,
                                                        int b0, int nbm1, int nbshift) {
    __shared__ float ldr[64][65];   // odd word stride -> conflict-free both phases
    __shared__ float ldi[64][65];
    int wg = blockIdx.x;
    int bl = wg & nbm1;
    int rest = wg >> nbshift;
    int ft = rest & 63;            // 64 f-tiles
    int ct = rest >> 6;            // 4 c-tiles
    int f0 = ft << 6, c0 = ct << 6;
    int t = threadIdx.x;
    int cl = t & 63;
    int rq = t >> 6;               // 0..3
    const float scale = 1.0f / (4096.0f * 1.5f);
    int bg = b0 + bl;
    const float* xrb = xr + (size_t)bg * NF * NC;
    const float* xib = xi + (size_t)bg * NF * NC;
#pragma unroll
    for (int q = 0; q < 16; q++) {
        int r = q * 4 + rq;        // f-row in tile
        size_t idx = (size_t)(f0 + r) * NC + c0 + cl;   // consecutive cl -> coalesced
        ldr[cl][r] = xrb[idx] * scale;
        ldi[cl][r] = xib[idx] * scale;
    }
    __syncthreads();
    int fl = t & 63;
#pragma unroll
    for (int q = 0; q < 16; q++) {
        int cr = q * 4 + rq;       // c-row in tile
        fin[((size_t)(bl * NC + c0 + cr)) * NF + f0 + fl] =
            make_float2(ldr[cr][fl], ldi[cr][fl]);      // consecutive fl -> coalesced
    }
}

// ---------------- stage B: IFFT-4096 in place over fin[b,c,:], Stockham radix-16 ----------------
#define IPAD(a) ((a) + ((a) >> 4))

template<int P>
__device__ __forceinline__ void pass16(float2* S, int t, float sgn) {
    const int k = t & (P - 1);
    float2 u[16];
#pragma unroll
    for (int r = 0; r < 16; r++) u[r] = S[IPAD(t + 256 * r)];
    __syncthreads();
    if (P > 1) {
        float ab = sgn * (TWO_PI_F / (16.0f * (float)P)) * (float)k;
#pragma unroll
        for (int r = 1; r < 16; r++) {
            float sn, cs; __sincosf(ab * (float)r, &sn, &cs);
            u[r] = cmul(u[r], make_float2(cs, sn));
        }
    }
    dft16(u, sgn);
    const int base = 16 * P * (t / P) + k;
#pragma unroll
    for (int j = 0; j < 16; j++) {
        const int sl = ((j & 3) << 2) | (j >> 2);
        S[IPAD(base + j * P)] = u[sl];
    }
    __syncthreads();
}

__global__ __launch_bounds__(256) void ifft4096_kernel(float2* __restrict__ fin,
                                                       int bmask, int bshift) {
    __shared__ float2 S[4352];   // 34 KiB
    int wg = blockIdx.x;
    int bl = wg & bmask;
    int c = wg >> bshift;
    int t = threadIdx.x;
    size_t base = ((size_t)(bl * NC + c)) * NF;
#pragma unroll
    for (int q = 0; q < 16; q++) {
        int f = t + 256 * q;
        S[IPAD(f)] = fin[base + f];    // coalesced 8B/lane
    }
    __syncthreads();
    pass16<1>(S, t, 1.0f);
    pass16<16>(S, t, 1.0f);
    pass16<256>(S, t, 1.0f);
#pragma unroll
    for (int q = 0; q < 16; q++) {
        int f = t + 256 * q;
        fin[base + f] = S[IPAD(f)];
    }
}

// ---------------- stage C1: banded Gram, FMA-dense with fp64 accumulation ----------------
// WG = (bl, ks: 32-k tile, ch: 128-m chunk). Bulk-load 40 rows (32 + 8 halo) into planar
// re/im LDS, row stride 136. Thread (kk, sg) owns all 8 d-accumulators for k = k0+kk over
// m = sg + 8*mm: per mm, 18 b32 LDS reads feed 32 f64 FMAs (no shuffles in loop); 3-step
// f64 sg-reduce at end. fp64 accumulation is strictly tighter than any prior f32 tree ->
// keeps the chaotic phase recurrence on the reference trajectory.
#define GSTR 136
__global__ __launch_bounds__(256) void gram_kernel(const float2* __restrict__ fin,
                                                   float2* __restrict__ gpart) {
    __shared__ float lre[40 * GSTR];   // 21.25 KiB
    __shared__ float lim[40 * GSTR];   // 21.25 KiB
    int wg = blockIdx.x;            // ((bl*8)+ks)*32 + ch
    int bl = wg >> 8;
    int ks = (wg >> 5) & 7;
    int ch = wg & 31;
    int m0 = ch * CH;
    int k0 = ks * 32;
    int t = threadIdx.x;
    // bulk load: 40 rows x 128 float2, coalesced (2 rows per 256-thread iteration)
#pragma unroll
    for (int q = 0; q < 20; q++) {
        int e = t + 256 * q;
        int row = e >> 7;
        int m = e & 127;
        int gk = k0 - 8 + row;
        float2 v = (gk >= 0) ? fin[((size_t)(bl * NC + gk)) * NF + m0 + m]
                             : make_float2(0.f, 0.f);
        lre[row * GSTR + m] = v.x;
        lim[row * GSTR + m] = v.y;
    }
    __syncthreads();
    int kk = t >> 3;                // 0..31
    int sg = t & 7;                 // 0..7
    double accx[8], accy[8];
#pragma unroll
    for (int d = 0; d < 8; d++) { accx[d] = 0.0; accy[d] = 0.0; }
    const float* bre = &lre[(kk + 8) * GSTR + sg];
    const float* bim = &lim[(kk + 8) * GSTR + sg];
    const float* are = &lre[kk * GSTR + sg];
    const float* aim = &lim[kk * GSTR + sg];
#pragma unroll
    for (int mm = 0; mm < 16; mm++) {
        int mo = 8 * mm;
        double bx = (double)bre[mo];
        double by = (double)bim[mo];
#pragma unroll
        for (int d = 1; d <= 8; d++) {
            int ao = (8 - d) * GSTR + mo;   // compile-time constant per (d, mm)
            double ax = (double)are[ao];
            double ay = (double)aim[ao];
            accx[d - 1] = fma(ay, by, fma(ax, bx, accx[d - 1]));   // += Re(conj(a)*b)
            accy[d - 1] = fma(ax, by, fma(-ay, bx, accy[d - 1]));  // += Im(conj(a)*b)
        }
    }
    // reduce over the 8 sg strips (lanes t^1, t^2, t^4 share kk)
    size_t gbase = ((size_t)(bl * 32 + ch) * NC + (k0 + kk)) * 8;
#pragma unroll
    for (int d = 0; d < 8; d++) {
        double sx = accx[d], sy = accy[d];
#pragma unroll
        for (int off = 1; off <= 4; off <<= 1) {
            sx += __shfl_xor(sx, off);
            sy += __shfl_xor(sy, off);
        }
        if (sg == 0)   // d>k entries stay exact zeros -> no poison downstream
            gpart[gbase + d] = make_float2((float)sx, (float)sy);
    }
}

// ---------------- stage C2a: sum Gram partials over 32 chunks ----------------
__global__ void gsum_kernel(const float2* __restrict__ gpart, float2* __restrict__ gs, int total) {
    int e = blockIdx.x * blockDim.x + threadIdx.x;
    if (e >= total) return;
    int bl = e >> 11;
    int kd = e & 2047;
    float2 s = make_float2(0.f, 0.f);
    for (int ch = 0; ch < 32; ch++) {
        float2 v = gpart[((size_t)(bl * 32 + ch)) * 2048 + kd];
        s.x += v.x; s.y += v.y;
    }
    gs[e] = s;
}

// ---------------- stage C2b: scalar phase recurrence, sched_barrier-pinned prefetch ----------------
#define SCAN_STEP(A0, A1, A2, A3, KIDX)  do {                                  \
    float rx0 = p1.x*A0.x - p1.y*A0.y, ry0 = p1.x*A0.y + p1.y*A0.x;            \
    float rx1 = p2.x*A0.z - p2.y*A0.w, ry1 = p2.x*A0.w + p2.y*A0.z;            \
    float rx2 = p3.x*A1.x - p3.y*A1.y, ry2 = p3.x*A1.y + p3.y*A1.x;            \
    float rx3 = p4.x*A1.z - p4.y*A1.w, ry3 = p4.x*A1.w + p4.y*A1.z;            \
    float rx4 = p5.x*A2.x - p5.y*A2.y, ry4 = p5.x*A2.y + p5.y*A2.x;            \
    float rx5 = p6.x*A2.z - p6.y*A2.w, ry5 = p6.x*A2.w + p6.y*A2.z;            \
    float rx6 = p7.x*A3.x - p7.y*A3.y, ry6 = p7.x*A3.y + p7.y*A3.x;            \
    float rx7 = p8.x*A3.z - p8.y*A3.w, ry7 = p8.x*A3.w + p8.y*A3.z;            \
    float sx = ((rx0 + rx1) + (rx2 + rx3)) + ((rx4 + rx5) + (rx6 + rx7));      \
    float sy = ((ry0 + ry1) + (ry2 + ry3)) + ((ry4 + ry5) + (ry6 + ry7));      \
    float inv = rsqrtf(sx * sx + sy * sy);                                     \
    float2 np = make_float2(sx * inv, sy * inv);                               \
    phase[t * NC + (KIDX)] = np;                                               \
    p8 = p7; p7 = p6; p6 = p5; p5 = p4; p4 = p3; p3 = p2; p2 = p1; p1 = np;    \
} while (0)

#define SCAN_LOADG4(BUF, KBASE)  do {                                          \
    _Pragma("unroll") for (int j = 0; j < 4; j++) {                            \
        _Pragma("unroll") for (int q = 0; q < 4; q++)                          \
            BUF[j][q] = gb4[((KBASE) + j) * 4 + q];                            \
    }                                                                          \
} while (0)

#define SCAN_GRP4(BUF, KBASE, FIRST)  do {                                     \
    _Pragma("unroll") for (int j = 0; j < 4; j++) {                            \
        if (FIRST && j == 0) {                                                 \
            phase[t * NC] = make_float2(1.f, 0.f);                             \
        } else {                                                               \
            SCAN_STEP(BUF[j][0], BUF[j][1], BUF[j][2], BUF[j][3], (KBASE) + j);\
        }                                                                      \
    }                                                                          \
} while (0)

__global__ __launch_bounds__(64, 1) void scan_copy_kernel(const float2* __restrict__ gs,
                                                          float2* __restrict__ phase, int nb,
                                                          const float4* __restrict__ csrc,
                                                          float4* __restrict__ cdst, int cn4) {
    if (blockIdx.x != 0) {
        int i = (blockIdx.x - 1) * 64 + threadIdx.x;
        int stride = (gridDim.x - 1) * 64;
        for (; i < cn4; i += stride) cdst[i] = csrc[i];
        return;
    }
    int t = threadIdx.x;
    if (t >= nb) return;
    const float4* gb4 = (const float4*)(gs + (size_t)t * 2048);   // 256 rows x 4 float4
    float2 z = make_float2(0.f, 0.f);
    float2 p1 = make_float2(1.f, 0.f);
    float2 p2 = z, p3 = z, p4 = z, p5 = z, p6 = z, p7 = z, p8 = z;
    float4 GA[4][4], GB[4][4];
    SCAN_LOADG4(GA, 0);
    for (int g2 = 0; g2 < 32; g2++) {
        int k0 = g2 * 8;
        SCAN_LOADG4(GB, k0 + 4);
        __builtin_amdgcn_sched_barrier(0);   // pin GB loads before GA compute
        if (g2 == 0) { SCAN_GRP4(GA, k0, true); } else { SCAN_GRP4(GA, k0, false); }
        if (g2 < 31) SCAN_LOADG4(GA, k0 + 8);
        __builtin_amdgcn_sched_barrier(0);   // pin GA-next loads before GB compute
        SCAN_GRP4(GB, k0 + 4, false);
    }
}

// ---------------- stage C3 (fallback paths only): fin *= conj(phase) ----------------
__global__ void scale_kernel(float4* __restrict__ fin4, const float2* __restrict__ phase, int n4) {
    int i = blockIdx.x * blockDim.x + threadIdx.x;
    if (i >= n4) return;
    int row = i >> 11;
    float2 ph = phase[row];
    float4 v = fin4[i];
    fin4[i] = make_float4(v.x*ph.x + v.y*ph.y, v.y*ph.x - v.x*ph.y,
                          v.z*ph.x + v.w*ph.y, v.w*ph.x - v.z*ph.y);
}

// ---------------- stage D: FFT-512 over c (zero-padded), Stockham radix-8, fused conj(phase) ----------------
#define FPAD 516   // row stride (float2) for [8][516] LDS

template<int P, bool ZTOP>
__device__ __forceinline__ void pass8x(float2* L, int fp, int i2, float sgn) {
    const int ia = i2, ib = i2 + 32;
    const int ka = ia & (P - 1), kb = ib & (P - 1);
    float2 ua[8], ub[8];
#pragma unroll
    for (int r = 0; r < 8; r++) {
        if (ZTOP && r >= 4) {
            ua[r] = make_float2(0.f, 0.f);
            ub[r] = make_float2(0.f, 0.f);
        } else {
            ua[r] = L[fp * FPAD + ia + 64 * r];
            ub[r] = L[fp * FPAD + ib + 64 * r];
        }
    }
    __syncthreads();
    if (P > 1) {
        float aba = sgn * (TWO_PI_F / (8.0f * (float)P)) * (float)ka;
        float abb = sgn * (TWO_PI_F / (8.0f * (float)P)) * (float)kb;
#pragma unroll
        for (int r = 1; r < 8; r++) {
            float sn, cs;
            __sincosf(aba * (float)r, &sn, &cs);
            ua[r] = cmul(ua[r], make_float2(cs, sn));
            __sincosf(abb * (float)r, &sn, &cs);
            ub[r] = cmul(ub[r], make_float2(cs, sn));
        }
    }
    float2 va[8], vb[8];
    dft8(ua, va, sgn);
    dft8(ub, vb, sgn);
    const int basea = 8 * P * (ia / P) + ka;
    const int baseb = 8 * P * (ib / P) + kb;
#pragma unroll
    for (int r = 0; r < 8; r++) {
        L[fp * FPAD + basea + r * P] = va[r];
        L[fp * FPAD + baseb + r * P] = vb[r];
    }
    __syncthreads();
}

__global__ __launch_bounds__(256) void fft512_kernel(const float2* __restrict__ fin,
                                                     const float2* __restrict__ ph,   // may be null
                                                     float* __restrict__ outr,
                                                     float2* __restrict__ outc,
                                                     int b0, int realOnly) {
    __shared__ float2 L[8 * FPAD];   // 33 KiB
    int wg = blockIdx.x;             // bl*512 + ftile
    int bl = wg >> 9;
    int f0 = (wg & 511) * 8;
    int t = threadIdx.x;
    int fpp = t & 7;
    int cg = t >> 3;                 // 0..31
#pragma unroll
    for (int it = 0; it < 8; it++) {
        int c = it * 32 + cg;
        float2 v = fin[((size_t)(bl * NC + c)) * NF + f0 + fpp];
        if (ph) {
            float2 p = ph[bl * NC + c];
            v = make_float2(v.x * p.x + v.y * p.y, v.y * p.x - v.x * p.y);  // f*conj(ph)
        }
        L[fpp * FPAD + c] = v;
    }
    __syncthreads();
    int fp = t & 7;
    int i2 = t >> 3;                 // 0..31
    pass8x<1, true >(L, fp, i2, -1.0f);
    pass8x<8, false>(L, fp, i2, -1.0f);
    pass8x<64, false>(L, fp, i2, -1.0f);
    size_t ob = ((size_t)((b0 + bl) * NF + f0)) * NJ;
    if (realOnly) {
#pragma unroll
        for (int fp2 = 0; fp2 < 8; fp2++)
#pragma unroll
            for (int jq = 0; jq < 2; jq++) {
                int j = t + 256 * jq;
                outr[ob + (size_t)fp2 * NJ + j] = L[fp2 * FPAD + j].x;
            }
    } else {
#pragma unroll
        for (int fp2 = 0; fp2 < 8; fp2++)
#pragma unroll
            for (int jq = 0; jq < 2; jq++) {
                int j = t + 256 * jq;
                outc[ob + (size_t)fp2 * NJ + j] = L[fp2 * FPAD + j];
            }
    }
}

// ---------------- output 0 writers (fallback paths) ----------------
__global__ void copy_kernel(const float4* __restrict__ src, float4* __restrict__ dst, int n4) {
    int i = blockIdx.x * blockDim.x + threadIdx.x;
    int stride = gridDim.x * blockDim.x;
    for (; i < n4; i += stride) dst[i] = src[i];
}
__global__ void pack_x_kernel(const float2* __restrict__ xr, const float2* __restrict__ xi,
                              float4* __restrict__ out, int n4) {
    int i = blockIdx.x * blockDim.x + threadIdx.x;
    int stride = gridDim.x * blockDim.x;
    for (; i < n4; i += stride) {
        float2 r = xr[i], m = xi[i];
        out[i] = make_float4(r.x, m.x, r.y, m.y);
    }
}

extern "C" void kernel_launch(void* const* d_in, const int* in_sizes, int n_in,
                              void* d_out, int out_size, void* d_ws, size_t ws_size,
                              hipStream_t stream) {
    const float* xr = (const float*)d_in[0];
    const float* xi = (const float*)d_in[1];
    float* out = (float*)d_out;

    if (out_size < 40000000) {
        // real-only outputs: out0 = x_real (8388608 f), out3 = Re(out3) (16777216 f)
        float* out0r = out;
        float* out3r = out + 8388608;
        size_t need = (size_t)(8388608 + 524288 + 16384 + 2048) * sizeof(float2);
        if (ws_size >= need) {
            float2* fin   = (float2*)d_ws;
            float2* gpart = fin + 8388608;
            float2* gsb   = gpart + 524288;
            float2* phase = gsb + 16384;
            transpose_kernel<<<8 * 256, 256, 0, stream>>>(xr, xi, fin, 0, 7, 3);
            ifft4096_kernel<<<8 * NC, 256, 0, stream>>>(fin, 7, 3);
            gram_kernel<<<8 * 256, 256, 0, stream>>>(fin, gpart);
            gsum_kernel<<<(8 * 2048) / 256, 256, 0, stream>>>(gpart, gsb, 8 * 2048);
            // block 0: serial scan; blocks 1..2048: out0 copy (independent, overlapped)
            scan_copy_kernel<<<2049, 64, 0, stream>>>(gsb, phase, 8,
                                                      (const float4*)xr, (float4*)out0r, 2097152);
            fft512_kernel<<<8 * 512, 256, 0, stream>>>(fin, phase, out3r, nullptr, 0, 1);
        } else {
            // two batch-half passes; fin in out0 region; gram scratch in out3 tail
            float2* fin   = (float2*)out0r;
            float2* o3f2  = (float2*)out3r;
            float2* gpart = o3f2 + (8388608 - 262144 - 8192 - 1024);
            float2* gsb   = o3f2 + (8388608 - 8192 - 1024);
            float2* phase = o3f2 + (8388608 - 1024);
            for (int p = 0; p < 2; p++) {
                int b0 = p * 4;
                transpose_kernel<<<4 * 256, 256, 0, stream>>>(xr, xi, fin, b0, 3, 2);
                ifft4096_kernel<<<4 * NC, 256, 0, stream>>>(fin, 3, 2);
                gram_kernel<<<4 * 256, 256, 0, stream>>>(fin, gpart);
                gsum_kernel<<<(4 * 2048) / 256, 256, 0, stream>>>(gpart, gsb, 4 * 2048);
                scan_copy_kernel<<<1, 64, 0, stream>>>(gsb, phase, 4, nullptr, nullptr, 0);
                scale_kernel<<<4 * 2048, 256, 0, stream>>>((float4*)fin, phase, 4 * 524288);
                fft512_kernel<<<4 * 512, 256, 0, stream>>>(fin, nullptr, out3r, nullptr, b0, 1);
            }
            copy_kernel<<<2048, 256, 0, stream>>>((const float4*)xr, (float4*)out0r, 2097152);
        }
    } else {
        // defensive path: complex outputs as float pairs
        float2* out0f2 = (float2*)out;
        float2* out3f2 = (float2*)(out + 16777216);
        float2* fin   = out0f2;
        float2* gpart = out3f2 + (16777216 - 524288 - 16384 - 2048);
        float2* gsb   = out3f2 + (16777216 - 16384 - 2048);
        float2* phase = out3f2 + (16777216 - 2048);
        transpose_kernel<<<8 * 256, 256, 0, stream>>>(xr, xi, fin, 0, 7, 3);
        ifft4096_kernel<<<8 * NC, 256, 0, stream>>>(fin, 7, 3);
        gram_kernel<<<8 * 256, 256, 0, stream>>>(fin, gpart);
        gsum_kernel<<<(8 * 2048) / 256, 256, 0, stream>>>(gpart, gsb, 8 * 2048);
        scan_copy_kernel<<<1, 64, 0, stream>>>(gsb, phase, 8, nullptr, nullptr, 0);
        scale_kernel<<<8 * 2048, 256, 0, stream>>>((float4*)fin, phase, 8 * 524288);
        fft512_kernel<<<8 * 512, 256, 0, stream>>>(fin, nullptr, nullptr, out3f2, 0, 0);
        pack_x_kernel<<<4096, 256, 0, stream>>>((const float2*)xr, (const float2*)xi,
                                                (float4*)out0f2, 4194304);
    }
}